// Round 4
// baseline (105732.092 us; speedup 1.0000x reference)
//
#include <hip/hip_runtime.h>
#include <hip/hip_bf16.h>
#include <math.h>

typedef __hip_bfloat16 bf16;

#define B_   8
#define T_   32
#define C_   4
#define HW_  84
#define P_   14
#define GP_  6
#define LOBS 36
#define S_   39
#define L_   (T_ * S_)          // 1248
#define D_   512
#define NH_  8
#define DH_  64
#define NL_  6
#define DFF_ 2048
#define NRET 120
#define NACT 18
#define NREW 3

#define ROWS (B_ * L_)          // 9984
#define OBS_ROWS (B_ * T_ * LOBS) // 9216
#define PK   (C_ * P_ * P_)     // 784

#define OFF_H    0
#define OFF_A    (ROWS * D_)
#define OFF_QKV  (OFF_A + ROWS * D_)
#define OFF_FFN  (OFF_QKV + ROWS * 3 * D_)
#define OFF_FLAG (OFF_FFN + ROWS * DFF_)
#define WS_FLOATS (OFF_FLAG + 16)

static __device__ __forceinline__ float b2f(bf16 x) { return __bfloat162float(x); }

// dtype-adaptive input load: isbf=1 -> bf16 buffer, else fp32
static __device__ __forceinline__ float ldf(const void* p, size_t i, int isbf) {
    if (isbf) return b2f(((const bf16*)p)[i]);
    return ((const float*)p)[i];
}

__global__ void sniff_kernel(const void* frames, int* flagp) {
    __shared__ int cnt;
    if (threadIdx.x == 0) cnt = 0;
    __syncthreads();
    const unsigned short* u = (const unsigned short*)frames;
    unsigned short v = u[2 * threadIdx.x];
    int e = (v >> 7) & 0xFF;
    if (e >= 100 && e <= 140) atomicAdd(&cnt, 1);
    __syncthreads();
    if (threadIdx.x == 0) *flagp = (cnt >= 160) ? 1 : 0;
}

// sentinel path: unmistakable output if ws too small
__global__ void sentinel_kernel(float* out, int n) {
    int i = blockIdx.x * 256 + threadIdx.x;
    if (i < n) out[i] = 100.0f;
}

// ---------------- patchify ----------------
__global__ void patchify_kernel(const void* __restrict__ frames,
                                float* __restrict__ Xp,
                                const int* __restrict__ flagp) {
    int isbf = *flagp;
    int idx = blockIdx.x * 256 + threadIdx.x;
    if (idx >= OBS_ROWS * PK) return;
    int r = idx / PK, c = idx % PK;
    int bt = r / LOBS, p = r % LOBS;
    int gy = p / GP_, gx = p % GP_;
    int ch = c / (P_ * P_), rem = c % (P_ * P_);
    int py = rem / P_, px = rem % P_;
    size_t src = (((size_t)bt * C_ + ch) * HW_ + gy * P_ + py) * HW_ + gx * P_ + px;
    Xp[idx] = ldf(frames, src, isbf);
}

// ---------------- naive GEMM: one thread per output element ----------------
// C[r,n] = act( sum_k A[r,k]*Bw[k,n] + bias[n] ) + residual[r,n]
__global__ void gemm_naive(const float* __restrict__ A,
                           const void* __restrict__ Bw, size_t bwoff,
                           const void* __restrict__ bias, size_t bioff,
                           const float* __restrict__ residual,
                           float* __restrict__ C,
                           int M, int N, int K, int do_gelu,
                           const int* __restrict__ flagp) {
    int isbf = *flagp;
    long long idx = (long long)blockIdx.x * 256 + threadIdx.x;
    if (idx >= (long long)M * N) return;
    int r = (int)(idx / N), n = (int)(idx % N);
    float acc = 0.0f;
    const float* Ar = A + (size_t)r * K;
    for (int k = 0; k < K; ++k)
        acc += Ar[k] * ldf(Bw, bwoff + (size_t)k * N + n, isbf);
    if (bias) acc += ldf(bias, bioff + n, isbf);
    if (do_gelu) acc = 0.5f * acc * (1.0f + erff(acc * 0.70710678118654752f));
    if (residual) acc += residual[(size_t)r * N + n];
    C[(size_t)r * N + n] = acc;
}

// ---------------- assemble tokens + embeddings ----------------
__global__ void assemble_kernel(const float* __restrict__ obs,
                                const int* __restrict__ rtg,
                                const int* __restrict__ act,
                                const int* __restrict__ rew,
                                const void* __restrict__ retE,
                                const void* __restrict__ actE,
                                const void* __restrict__ rewE,
                                const void* __restrict__ posE,
                                const void* __restrict__ typeE,
                                float* __restrict__ h,
                                const int* __restrict__ flagp) {
    int isbf = *flagp;
    int idx = blockIdx.x * 256 + threadIdx.x;
    if (idx >= ROWS * D_) return;
    int d = idx & (D_ - 1);
    int bl = idx / D_;
    int l = bl % L_, b = bl / L_;
    int t = l / S_, off = l % S_;
    int bt = b * T_ + t;
    float v;
    int ty;
    if (off < LOBS) {
        v = obs[((size_t)bt * LOBS + off) * D_ + d];
        ty = 0;
    } else if (off == LOBS) {
        v = ldf(retE, (size_t)rtg[bt] * D_ + d, isbf);
        ty = 1;
    } else if (off == LOBS + 1) {
        v = ldf(actE, (size_t)act[bt] * D_ + d, isbf);
        ty = 2;
    } else {
        v = ldf(rewE, (size_t)rew[bt] * D_ + d, isbf);
        ty = 3;
    }
    v += ldf(posE, (size_t)l * D_ + d, isbf) + ldf(typeE, (size_t)ty * D_ + d, isbf);
    h[idx] = v;
}

// ---------------- naive LayerNorm: one block per row, serial reductions ----------------
__global__ void ln_naive(const float* __restrict__ x,
                         const void* __restrict__ g, size_t goff,
                         const void* __restrict__ bb, size_t boff,
                         float* __restrict__ y,
                         const int* __restrict__ flagp) {
    int isbf = *flagp;
    int row = blockIdx.x;
    const float* xr = x + (size_t)row * D_;
    float* yr = y + (size_t)row * D_;
    int tid = threadIdx.x;  // 256 threads
    __shared__ float sm[256];
    __shared__ float stat[2];
    float v0 = xr[tid], v1 = xr[tid + 256];
    sm[tid] = v0 + v1;
    __syncthreads();
    if (tid == 0) {
        float s = 0.0f;
        for (int i = 0; i < 256; ++i) s += sm[i];
        stat[0] = s * (1.0f / 512.0f);
    }
    __syncthreads();
    float mean = stat[0];
    float d0 = v0 - mean, d1 = v1 - mean;
    sm[tid] = d0 * d0 + d1 * d1;
    __syncthreads();
    if (tid == 0) {
        float s = 0.0f;
        for (int i = 0; i < 256; ++i) s += sm[i];
        stat[1] = rsqrtf(s * (1.0f / 512.0f) + 1e-5f);
    }
    __syncthreads();
    float rstd = stat[1];
    yr[tid]       = d0 * rstd * ldf(g, goff + tid, isbf)       + ldf(bb, boff + tid, isbf);
    yr[tid + 256] = d1 * rstd * ldf(g, goff + tid + 256, isbf) + ldf(bb, boff + tid + 256, isbf);
}

// ---------------- naive attention: one block (64 threads) per (q, head, batch) ----------
// Mirrors the reference mask exactly: softmax over ALL L keys with +(-1e9) for disallowed.
__global__ void attn_naive(const float* __restrict__ qkv,
                           float* __restrict__ out) {
    int q_pos = blockIdx.x, hh = blockIdx.y, b = blockIdx.z;
    int tid = threadIdx.x;  // 64 threads
    __shared__ float q_sh[DH_];
    __shared__ float sc[L_];
    __shared__ float part[64];
    __shared__ float stat[2];
    const float* qkv_b = qkv + (size_t)b * L_ * (3 * D_);
    q_sh[tid] = qkv_b[(size_t)q_pos * (3 * D_) + hh * DH_ + tid];
    __syncthreads();
    int step_q = q_pos / S_, off_q = q_pos % S_;
    int obs_q = (off_q < LOBS) ? 1 : 0;
    for (int k = tid; k < L_; k += 64) {
        int step_k = k / S_, off_k = k % S_;
        int allowed = (k <= q_pos) || (obs_q && (off_k < LOBS) && (step_k == step_q));
        const float* kr = qkv_b + (size_t)k * (3 * D_) + D_ + hh * DH_;
        float dot = 0.0f;
        for (int d = 0; d < DH_; ++d) dot += q_sh[d] * kr[d];
        sc[k] = dot * 0.125f + (allowed ? 0.0f : -1e9f);
    }
    __syncthreads();
    float lm = -3e38f;
    for (int k = tid; k < L_; k += 64) lm = fmaxf(lm, sc[k]);
    part[tid] = lm;
    __syncthreads();
    if (tid == 0) {
        float m = part[0];
        for (int i = 1; i < 64; ++i) m = fmaxf(m, part[i]);
        stat[0] = m;
    }
    __syncthreads();
    float m = stat[0];
    float ls = 0.0f;
    for (int k = tid; k < L_; k += 64) {
        float p = expf(sc[k] - m);
        sc[k] = p;
        ls += p;
    }
    part[tid] = ls;
    __syncthreads();
    if (tid == 0) {
        float s = 0.0f;
        for (int i = 0; i < 64; ++i) s += part[i];
        stat[1] = s;
    }
    __syncthreads();
    float inv_l = 1.0f / stat[1];
    float o = 0.0f;
    for (int k = 0; k < L_; ++k)
        o += sc[k] * qkv_b[(size_t)k * (3 * D_) + 2 * D_ + hh * DH_ + tid];
    out[((size_t)b * L_ + q_pos) * D_ + hh * DH_ + tid] = o * inv_l;
}

// ---------------- naive heads: one block per (b,t); FP32 output ----------------
__global__ void heads_naive(const float* __restrict__ h,
                            const void* __restrict__ hW_ret, const void* __restrict__ hb_ret,
                            const void* __restrict__ hW_act, const void* __restrict__ hb_act,
                            const void* __restrict__ hW_rew, const void* __restrict__ hb_rew,
                            float* __restrict__ out,
                            const int* __restrict__ flagp) {
    int isbf = *flagp;
    int bt = blockIdx.x;
    int b = bt / T_, t = bt % T_;
    size_t base = ((size_t)b * L_ + (size_t)t * S_) * D_;
    const float* hr = h + base + (size_t)(LOBS - 1) * D_;
    const float* ha = h + base + (size_t)LOBS * D_;
    const float* hw = h + base + (size_t)(LOBS + 1) * D_;
    int tid = threadIdx.x;
    if (tid < NRET) {
        float acc = ldf(hb_ret, tid, isbf);
        for (int k = 0; k < D_; ++k) acc += hr[k] * ldf(hW_ret, (size_t)k * NRET + tid, isbf);
        out[(size_t)bt * NRET + tid] = acc;
    } else if (tid < NRET + NACT) {
        int n = tid - NRET;
        float acc = ldf(hb_act, n, isbf);
        for (int k = 0; k < D_; ++k) acc += ha[k] * ldf(hW_act, (size_t)k * NACT + n, isbf);
        out[(size_t)(B_ * T_ * NRET) + (size_t)bt * NACT + n] = acc;
    } else if (tid < NRET + NACT + NREW) {
        int n = tid - NRET - NACT;
        float acc = ldf(hb_rew, n, isbf);
        for (int k = 0; k < D_; ++k) acc += hw[k] * ldf(hW_rew, (size_t)k * NREW + n, isbf);
        out[(size_t)(B_ * T_ * (NRET + NACT)) + (size_t)bt * NREW + n] = acc;
    }
}

static inline int cdiv_ll(long long a, int b) { return (int)((a + b - 1) / b); }

extern "C" void kernel_launch(void* const* d_in, const int* in_sizes, int n_in,
                              void* d_out, int out_size, void* d_ws, size_t ws_size,
                              hipStream_t stream) {
    if (ws_size < (size_t)WS_FLOATS * sizeof(float)) {
        sentinel_kernel<<<(out_size + 255) / 256, 256, 0, stream>>>((float*)d_out, out_size);
        return;
    }
    const int* rtg     = (const int*)d_in[1];
    const int* actions = (const int*)d_in[2];
    const int* rewards = (const int*)d_in[3];

    float* ws  = (float*)d_ws;
    float* h   = ws + OFF_H;
    float* a   = ws + OFF_A;
    float* qkv = ws + OFF_QKV;
    float* ffn = ws + OFF_FFN;
    float* Xp  = ffn;                          // aliased, pre-layer-loop only
    float* obs = ffn + (size_t)OBS_ROWS * PK;
    int* flagp = (int*)(ws + OFF_FLAG);

    sniff_kernel<<<1, 256, 0, stream>>>(d_in[0], flagp);

    patchify_kernel<<<cdiv_ll((long long)OBS_ROWS * PK, 256), 256, 0, stream>>>(d_in[0], Xp, flagp);
    gemm_naive<<<cdiv_ll((long long)OBS_ROWS * D_, 256), 256, 0, stream>>>(
        Xp, d_in[4], 0, d_in[5], 0, nullptr, obs, OBS_ROWS, D_, PK, 0, flagp);

    assemble_kernel<<<cdiv_ll((long long)ROWS * D_, 256), 256, 0, stream>>>(
        obs, rtg, actions, rewards, d_in[6], d_in[7], d_in[8], d_in[9], d_in[10], h, flagp);

    for (int i = 0; i < NL_; ++i) {
        ln_naive<<<ROWS, 256, 0, stream>>>(h, d_in[15], (size_t)i * D_,
                                           d_in[16], (size_t)i * D_, a, flagp);
        gemm_naive<<<cdiv_ll((long long)ROWS * 3 * D_, 256), 256, 0, stream>>>(
            a, d_in[11], (size_t)i * D_ * 3 * D_, d_in[12], (size_t)i * 3 * D_,
            nullptr, qkv, ROWS, 3 * D_, D_, 0, flagp);
        attn_naive<<<dim3(L_, NH_, B_), 64, 0, stream>>>(qkv, a);
        gemm_naive<<<cdiv_ll((long long)ROWS * D_, 256), 256, 0, stream>>>(
            a, d_in[13], (size_t)i * D_ * D_, d_in[14], (size_t)i * D_,
            h, h, ROWS, D_, D_, 0, flagp);
        ln_naive<<<ROWS, 256, 0, stream>>>(h, d_in[17], (size_t)i * D_,
                                           d_in[18], (size_t)i * D_, a, flagp);
        gemm_naive<<<cdiv_ll((long long)ROWS * DFF_, 256), 256, 0, stream>>>(
            a, d_in[19], (size_t)i * D_ * DFF_, d_in[20], (size_t)i * DFF_,
            nullptr, ffn, ROWS, DFF_, D_, 1, flagp);
        gemm_naive<<<cdiv_ll((long long)ROWS * D_, 256), 256, 0, stream>>>(
            ffn, d_in[21], (size_t)i * DFF_ * D_, d_in[22], (size_t)i * D_,
            h, h, ROWS, D_, DFF_, 0, flagp);
    }

    heads_naive<<<B_ * T_, 256, 0, stream>>>(h, d_in[23], d_in[24], d_in[25],
                                             d_in[26], d_in[27], d_in[28],
                                             (float*)d_out, flagp);
}

// Round 5
// 4580.621 us; speedup vs baseline: 23.0825x; 23.0825x over previous
//
#include <hip/hip_runtime.h>
#include <hip/hip_bf16.h>
#include <math.h>

typedef unsigned short ushort_t;
typedef __attribute__((ext_vector_type(8))) short bf16x8;
typedef __attribute__((ext_vector_type(4))) float floatx4;

#define B_   8
#define T_   32
#define C_   4
#define HW_  84
#define P_   14
#define GP_  6
#define LOBS 36
#define S_   39
#define L_   (T_ * S_)          // 1248
#define D_   512
#define NH_  8
#define DH_  64
#define NL_  6
#define DFF_ 2048
#define NRET 120
#define NACT 18
#define NREW 3

#define ROWS (B_ * L_)          // 9984
#define OBS_ROWS (B_ * T_ * LOBS) // 9216
#define PK   (C_ * P_ * P_)     // 784
#define PKP  800                 // PK padded to %32

// workspace layout (float units)
#define OFF_H     0                         // fp32 9984*512
#define OFF_AB1   5111808                   // bf16 9984*512  (2,555,904 floats)
#define OFF_AB2   (OFF_AB1 + 2555904)
#define OFF_QKVB  (OFF_AB2 + 2555904)       // bf16 9984*1536 (7,667,712 floats)
#define OFF_FFNB  (OFF_QKVB + 7667712)      // bf16 9984*2048 (10,223,616 floats)
#define OFF_WB    (OFF_FFNB + 10223616)     // bf16 weights (9,641,984 floats)
#define WS_FLOATS (OFF_WB + 9641984 + 16)
// Xp (bf16 9216*800 = 3,686,400 floats) and obs (fp32 9216*512 = 4,718,592 floats)
// aliased into the FFNB region (used only before the layer loop).

static __device__ __forceinline__ float b2f_u(ushort_t u) {
    union { unsigned int u32; float f; } v; v.u32 = ((unsigned int)u) << 16; return v.f;
}
static __device__ __forceinline__ ushort_t f2b(float x) {
    union { float f; unsigned int u; } v; v.f = x;
    unsigned int r = v.u + 0x7FFFu + ((v.u >> 16) & 1u);
    return (ushort_t)(r >> 16);
}

__global__ void sentinel_kernel(float* out, int n) {
    int i = blockIdx.x * 256 + threadIdx.x;
    if (i < n) out[i] = 100.0f;
}

// ---------------- fp32 -> bf16 weight conversion ----------------
__global__ void cvt_kernel(const float* __restrict__ src, ushort_t* __restrict__ dst, int n) {
    int i = blockIdx.x * 256 + threadIdx.x;
    if (i < n) dst[i] = f2b(src[i]);
}

// patch_W (784x512) -> bf16 padded (800x512), pad rows zero
__global__ void cvt_patchw_kernel(const float* __restrict__ src, ushort_t* __restrict__ dst) {
    int i = blockIdx.x * 256 + threadIdx.x;
    if (i >= PKP * D_) return;
    int r = i / D_;
    dst[i] = (r < PK) ? f2b(src[i]) : (ushort_t)0;
}

// ---------------- patchify: frames fp32 -> Xp bf16 (9216 x 800, pad cols zero) --------
__global__ void patchify_kernel(const float* __restrict__ frames, ushort_t* __restrict__ Xp) {
    int idx = blockIdx.x * 256 + threadIdx.x;
    if (idx >= OBS_ROWS * PKP) return;
    int r = idx / PKP, c = idx % PKP;
    if (c >= PK) { Xp[idx] = 0; return; }
    int bt = r / LOBS, p = r % LOBS;
    int gy = p / GP_, gx = p % GP_;
    int ch = c / (P_ * P_), rem = c % (P_ * P_);
    int py = rem / P_, px = rem % P_;
    size_t src = (((size_t)bt * C_ + ch) * HW_ + gy * P_ + py) * HW_ + gx * P_ + px;
    Xp[idx] = f2b(frames[src]);
}

// ---------------- MFMA bf16 GEMM: 128x128 tile, BK=32 ----------------
// C = act(A@Bw + bias) [+ residual]; A MxK bf16, Bw KxN bf16, out fp32 (Cf) and/or bf16 (Cb).
// M%128==0, N%128==0, K%32==0.
__global__ __launch_bounds__(256) void gemm_mfma(
    const ushort_t* __restrict__ A, const ushort_t* __restrict__ Bw,
    const float* __restrict__ bias, const float* __restrict__ residual,
    float* __restrict__ Cf, ushort_t* __restrict__ Cb,
    int M, int N, int K, int do_gelu)
{
    __shared__ ushort_t As[128 * 40];   // [m][k], pad 8
    __shared__ ushort_t Bs[128 * 40];   // [n][k] transposed, pad 8
    int t = threadIdx.x;
    int lane = t & 63, w = t >> 6;
    int row0 = blockIdx.y * 128, col0 = blockIdx.x * 128;
    int moff = (w & 1) << 6, noff = (w >> 1) << 6;
    int fr = lane & 15, fk = (lane >> 4) << 3;
    floatx4 acc[4][4];
#pragma unroll
    for (int i = 0; i < 4; ++i)
#pragma unroll
        for (int j = 0; j < 4; ++j) acc[i][j] = (floatx4){0.f, 0.f, 0.f, 0.f};
    int ar = t >> 2, akc = (t & 3) << 3;      // A staging: 64 rows/iter, 8 k each
    int bn = t & 127, bkh = (t >> 7) << 4;    // B staging: thread owns (n, 16 k's)
    for (int k0 = 0; k0 < K; k0 += 32) {
#pragma unroll
        for (int rr = 0; rr < 128; rr += 64)
            *(bf16x8*)&As[(rr + ar) * 40 + akc] =
                *(const bf16x8*)(A + (size_t)(row0 + rr + ar) * K + k0 + akc);
        ushort_t tmp[16];
#pragma unroll
        for (int j = 0; j < 16; ++j)
            tmp[j] = Bw[(size_t)(k0 + bkh + j) * N + col0 + bn];
        *(bf16x8*)&Bs[bn * 40 + bkh] = *(bf16x8*)&tmp[0];
        *(bf16x8*)&Bs[bn * 40 + bkh + 8] = *(bf16x8*)&tmp[8];
        __syncthreads();
        bf16x8 af[4], bfr[4];
#pragma unroll
        for (int i = 0; i < 4; ++i)
            af[i] = *(const bf16x8*)&As[(moff + i * 16 + fr) * 40 + fk];
#pragma unroll
        for (int j = 0; j < 4; ++j)
            bfr[j] = *(const bf16x8*)&Bs[(noff + j * 16 + fr) * 40 + fk];
#pragma unroll
        for (int i = 0; i < 4; ++i)
#pragma unroll
            for (int j = 0; j < 4; ++j)
                acc[i][j] = __builtin_amdgcn_mfma_f32_16x16x32_bf16(af[i], bfr[j], acc[i][j], 0, 0, 0);
        __syncthreads();
    }
    // C/D layout (verified m89/m91): col = lane&15, row = (lane>>4)*4 + reg
    int rquad = (lane >> 4) << 2;
#pragma unroll
    for (int j = 0; j < 4; ++j) {
        int col = col0 + noff + j * 16 + fr;
        float bv = bias ? bias[col] : 0.0f;
#pragma unroll
        for (int i = 0; i < 4; ++i) {
#pragma unroll
            for (int r = 0; r < 4; ++r) {
                int row = row0 + moff + i * 16 + rquad + r;
                float v = acc[i][j][r] + bv;
                if (do_gelu) v = 0.5f * v * (1.0f + erff(v * 0.70710678118654752f));
                if (residual) v += residual[(size_t)row * N + col];
                if (Cf) Cf[(size_t)row * N + col] = v;
                if (Cb) Cb[(size_t)row * N + col] = f2b(v);
            }
        }
    }
}

// ---------------- assemble tokens + embeddings -> h fp32 ----------------
__global__ void assemble_kernel(const float* __restrict__ obs,
                                const int* __restrict__ rtg,
                                const int* __restrict__ act,
                                const int* __restrict__ rew,
                                const float* __restrict__ retE,
                                const float* __restrict__ actE,
                                const float* __restrict__ rewE,
                                const float* __restrict__ posE,
                                const float* __restrict__ typeE,
                                float* __restrict__ h) {
    int idx = blockIdx.x * 256 + threadIdx.x;
    if (idx >= ROWS * D_) return;
    int d = idx & (D_ - 1);
    int bl = idx / D_;
    int l = bl % L_, b = bl / L_;
    int t = l / S_, off = l % S_;
    int bt = b * T_ + t;
    float v;
    int ty;
    if (off < LOBS) {
        v = obs[((size_t)bt * LOBS + off) * D_ + d];
        ty = 0;
    } else if (off == LOBS) {
        v = retE[(size_t)rtg[bt] * D_ + d];
        ty = 1;
    } else if (off == LOBS + 1) {
        v = actE[(size_t)act[bt] * D_ + d];
        ty = 2;
    } else {
        v = rewE[(size_t)rew[bt] * D_ + d];
        ty = 3;
    }
    v += posE[(size_t)l * D_ + d] + typeE[(size_t)ty * D_ + d];
    h[idx] = v;
}

// ---------------- LayerNorm fp32 in -> bf16 out ----------------
__global__ __launch_bounds__(256) void ln_fast(const float* __restrict__ x,
                                               const float* __restrict__ g,
                                               const float* __restrict__ bb,
                                               ushort_t* __restrict__ y) {
    int row = blockIdx.x;
    const float* xr = x + (size_t)row * D_;
    ushort_t* yr = y + (size_t)row * D_;
    int tid = threadIdx.x;
    float v0 = xr[tid], v1 = xr[tid + 256];
    __shared__ float red[4];
    int lane = tid & 63, wid = tid >> 6;
    float s = v0 + v1;
#pragma unroll
    for (int off = 32; off > 0; off >>= 1) s += __shfl_down(s, off, 64);
    if (lane == 0) red[wid] = s;
    __syncthreads();
    float mean = (red[0] + red[1] + red[2] + red[3]) * (1.0f / 512.0f);
    __syncthreads();
    float d0 = v0 - mean, d1 = v1 - mean;
    float vs = d0 * d0 + d1 * d1;
#pragma unroll
    for (int off = 32; off > 0; off >>= 1) vs += __shfl_down(vs, off, 64);
    if (lane == 0) red[wid] = vs;
    __syncthreads();
    float var = (red[0] + red[1] + red[2] + red[3]) * (1.0f / 512.0f);
    float rstd = rsqrtf(var + 1e-5f);
    yr[tid]       = f2b(d0 * rstd * g[tid]       + bb[tid]);
    yr[tid + 256] = f2b(d1 * rstd * g[tid + 256] + bb[tid + 256]);
}

// ---------------- tiled flash attention: block = (64-q-tile, head, batch) ----------------
// qkvb: [b][l][1536] bf16 (Q|K|V each 512). out: [b][l][512] bf16.
__global__ __launch_bounds__(256) void attn_mt(const ushort_t* __restrict__ qkvb,
                                               ushort_t* __restrict__ outb)
{
    int qt = blockIdx.x, hh = blockIdx.y, b = blockIdx.z;
    int q0 = qt << 6;
    int t = threadIdx.x, lane = t & 63, w = t >> 6;
    __shared__ float Kf[64][68];
    __shared__ float Vf[64][68];
    __shared__ float Ss[64][67];
    __shared__ float pm[4][64];
    __shared__ float ps[4][64];
    const ushort_t* base = qkvb + (size_t)b * L_ * 1536;
    int sr = t >> 2, sc = (t & 3) << 4;   // staging: row 0..63, 16 cols
    // stage Q tile (via Kf), then pull own row into registers
    {
        int qrow = q0 + sr; if (qrow > L_ - 1) qrow = L_ - 1;
        const ushort_t* qp = base + (size_t)qrow * 1536 + hh * 64 + sc;
        bf16x8 v0 = *(const bf16x8*)qp, v1 = *(const bf16x8*)(qp + 8);
#pragma unroll
        for (int j = 0; j < 8; ++j) {
            Kf[sr][sc + j]     = b2f_u(((ushort_t*)&v0)[j]);
            Kf[sr][sc + 8 + j] = b2f_u(((ushort_t*)&v1)[j]);
        }
    }
    __syncthreads();
    float qreg[64];
#pragma unroll
    for (int d = 0; d < 64; ++d) qreg[d] = Kf[lane][d];
    __syncthreads();

    int q_glob = q0 + lane;
    int qvalid = q_glob < L_;
    int step_q = q_glob / S_;
    int off_q = q_glob - step_q * S_;
    int obs_q = (off_q < LOBS) ? 1 : 0;

    int qlast = q0 + 63; if (qlast > L_ - 1) qlast = L_ - 1;
    int kend_max = qlast;
    int we = (qlast / S_) * S_ + LOBS - 1;
    if (we > kend_max) kend_max = we;
    int ntiles = (kend_max >> 6) + 1;

    float m_run = -3.0e38f, l_run = 0.0f;
    float o[16];
#pragma unroll
    for (int j = 0; j < 16; ++j) o[j] = 0.0f;

    for (int kt = 0; kt < ntiles; ++kt) {
        int k0 = kt << 6;
        {
            int krow = k0 + sr; if (krow > L_ - 1) krow = L_ - 1;
            const ushort_t* kp = base + (size_t)krow * 1536 + 512 + hh * 64 + sc;
            const ushort_t* vp = base + (size_t)krow * 1536 + 1024 + hh * 64 + sc;
            bf16x8 a0 = *(const bf16x8*)kp, a1 = *(const bf16x8*)(kp + 8);
            bf16x8 c0 = *(const bf16x8*)vp, c1 = *(const bf16x8*)(vp + 8);
#pragma unroll
            for (int j = 0; j < 8; ++j) {
                Kf[sr][sc + j]     = b2f_u(((ushort_t*)&a0)[j]);
                Kf[sr][sc + 8 + j] = b2f_u(((ushort_t*)&a1)[j]);
                Vf[sr][sc + j]     = b2f_u(((ushort_t*)&c0)[j]);
                Vf[sr][sc + 8 + j] = b2f_u(((ushort_t*)&c1)[j]);
            }
        }
        __syncthreads();
        // scores: wave w handles 16 k's, lane = q row
        float pmax = -3.0e38f;
        for (int kk = 0; kk < 16; ++kk) {
            int k_loc = (w << 4) + kk;
            int k_glob = k0 + k_loc;
            float dot = 0.0f;
#pragma unroll
            for (int d = 0; d < 64; ++d) dot += qreg[d] * Kf[k_loc][d];
            int step_k = k_glob / S_;
            int off_k = k_glob - step_k * S_;
            int allowed = (k_glob <= q_glob) || (obs_q && (off_k < LOBS) && (step_k == step_q));
            float s = allowed ? dot * 0.125f : -1.0e9f;
            Ss[lane][k_loc] = s;
            pmax = fmaxf(pmax, s);
        }
        pm[w][lane] = pmax;
        __syncthreads();
        float m_tile = fmaxf(fmaxf(pm[0][lane], pm[1][lane]), fmaxf(pm[2][lane], pm[3][lane]));
        float m_new = fmaxf(m_run, m_tile);
        float alpha = __expf(m_run - m_new);
        float psum = 0.0f;
        for (int kk = 0; kk < 16; ++kk) {
            int k_loc = (w << 4) + kk;
            float p = __expf(Ss[lane][k_loc] - m_new);
            Ss[lane][k_loc] = p;
            psum += p;
        }
        ps[w][lane] = psum;
        __syncthreads();
        float l_new = l_run * alpha + ps[0][lane] + ps[1][lane] + ps[2][lane] + ps[3][lane];
#pragma unroll
        for (int j = 0; j < 16; ++j) o[j] *= alpha;
        for (int k = 0; k < 64; ++k) {
            float p = Ss[lane][k];
#pragma unroll
            for (int j = 0; j < 16; ++j) o[j] += p * Vf[k][(w << 4) + j];
        }
        m_run = m_new; l_run = l_new;
        __syncthreads();
    }
    if (qvalid) {
        float inv = 1.0f / l_run;
        ushort_t* op = outb + ((size_t)b * L_ + q_glob) * 512 + hh * 64 + (w << 4);
#pragma unroll
        for (int j = 0; j < 16; ++j) op[j] = f2b(o[j] * inv);
    }
}

// ---------------- heads: fp32 h + fp32 weights -> fp32 out ----------------
__global__ void heads_naive(const float* __restrict__ h,
                            const float* __restrict__ hW_ret, const float* __restrict__ hb_ret,
                            const float* __restrict__ hW_act, const float* __restrict__ hb_act,
                            const float* __restrict__ hW_rew, const float* __restrict__ hb_rew,
                            float* __restrict__ out) {
    int bt = blockIdx.x;
    int b = bt / T_, t = bt % T_;
    size_t base = ((size_t)b * L_ + (size_t)t * S_) * D_;
    const float* hr = h + base + (size_t)(LOBS - 1) * D_;
    const float* ha = h + base + (size_t)LOBS * D_;
    const float* hw = h + base + (size_t)(LOBS + 1) * D_;
    int tid = threadIdx.x;
    if (tid < NRET) {
        float acc = hb_ret[tid];
        for (int k = 0; k < D_; ++k) acc += hr[k] * hW_ret[(size_t)k * NRET + tid];
        out[(size_t)bt * NRET + tid] = acc;
    } else if (tid < NRET + NACT) {
        int n = tid - NRET;
        float acc = hb_act[n];
        for (int k = 0; k < D_; ++k) acc += ha[k] * hW_act[(size_t)k * NACT + n];
        out[(size_t)(B_ * T_ * NRET) + (size_t)bt * NACT + n] = acc;
    } else if (tid < NRET + NACT + NREW) {
        int n = tid - NRET - NACT;
        float acc = hb_rew[n];
        for (int k = 0; k < D_; ++k) acc += hw[k] * hW_rew[(size_t)k * NREW + n];
        out[(size_t)(B_ * T_ * (NRET + NACT)) + (size_t)bt * NREW + n] = acc;
    }
}

static inline int cdiv_i(long long a, int b) { return (int)((a + b - 1) / b); }

extern "C" void kernel_launch(void* const* d_in, const int* in_sizes, int n_in,
                              void* d_out, int out_size, void* d_ws, size_t ws_size,
                              hipStream_t stream) {
    if (ws_size < (size_t)WS_FLOATS * sizeof(float)) {
        sentinel_kernel<<<(out_size + 255) / 256, 256, 0, stream>>>((float*)d_out, out_size);
        return;
    }
    const float* frames  = (const float*)d_in[0];
    const int*   rtg     = (const int*)d_in[1];
    const int*   actions = (const int*)d_in[2];
    const int*   rewards = (const int*)d_in[3];

    float* ws   = (float*)d_ws;
    float* h    = ws + OFF_H;
    ushort_t* ab1  = (ushort_t*)(ws + OFF_AB1);
    ushort_t* ab2  = (ushort_t*)(ws + OFF_AB2);
    ushort_t* qkvb = (ushort_t*)(ws + OFF_QKVB);
    ushort_t* ffnb = (ushort_t*)(ws + OFF_FFNB);
    ushort_t* xpb  = (ushort_t*)(ws + OFF_FFNB);                 // alias (pre-loop)
    float*    obs  = ws + OFF_FFNB + 3686400;                    // alias (pre-loop)
    ushort_t* wpatch = (ushort_t*)(ws + OFF_WB);
    ushort_t* wqkv = wpatch + PKP * D_;                          // 409,600
    ushort_t* wo   = wqkv + NL_ * D_ * 3 * D_;                   // +4,718,592
    ushort_t* w1   = wo + NL_ * D_ * D_;                         // +1,572,864
    ushort_t* w2   = w1 + NL_ * D_ * DFF_;                       // +6,291,456

    // ---- weight conversion fp32 -> bf16 ----
    cvt_patchw_kernel<<<cdiv_i(PKP * D_, 256), 256, 0, stream>>>((const float*)d_in[4], wpatch);
    cvt_kernel<<<cdiv_i(NL_ * D_ * 3 * D_, 256), 256, 0, stream>>>((const float*)d_in[11], wqkv, NL_ * D_ * 3 * D_);
    cvt_kernel<<<cdiv_i(NL_ * D_ * D_, 256), 256, 0, stream>>>((const float*)d_in[13], wo, NL_ * D_ * D_);
    cvt_kernel<<<cdiv_i(NL_ * D_ * DFF_, 256), 256, 0, stream>>>((const float*)d_in[19], w1, NL_ * D_ * DFF_);
    cvt_kernel<<<cdiv_i(NL_ * DFF_ * D_, 256), 256, 0, stream>>>((const float*)d_in[21], w2, NL_ * DFF_ * D_);

    // ---- patchify + patch embed ----
    patchify_kernel<<<cdiv_i((long long)OBS_ROWS * PKP, 256), 256, 0, stream>>>(frames, xpb);
    gemm_mfma<<<dim3(D_ / 128, OBS_ROWS / 128), 256, 0, stream>>>(
        xpb, wpatch, (const float*)d_in[5], nullptr, obs, nullptr, OBS_ROWS, D_, PKP, 0);

    // ---- assemble sequence ----
    assemble_kernel<<<cdiv_i((long long)ROWS * D_, 256), 256, 0, stream>>>(
        obs, rtg, actions, rewards,
        (const float*)d_in[6], (const float*)d_in[7], (const float*)d_in[8],
        (const float*)d_in[9], (const float*)d_in[10], h);

    // ---- transformer layers ----
    for (int i = 0; i < NL_; ++i) {
        ln_fast<<<ROWS, 256, 0, stream>>>(h, (const float*)d_in[15] + i * D_,
                                          (const float*)d_in[16] + i * D_, ab1);
        gemm_mfma<<<dim3(3 * D_ / 128, ROWS / 128), 256, 0, stream>>>(
            ab1, wqkv + (size_t)i * D_ * 3 * D_, (const float*)d_in[12] + i * 3 * D_,
            nullptr, nullptr, qkvb, ROWS, 3 * D_, D_, 0);
        attn_mt<<<dim3((L_ + 63) / 64, NH_, B_), 256, 0, stream>>>(qkvb, ab2);
        gemm_mfma<<<dim3(D_ / 128, ROWS / 128), 256, 0, stream>>>(
            ab2, wo + (size_t)i * D_ * D_, (const float*)d_in[14] + i * D_,
            h, h, nullptr, ROWS, D_, D_, 0);
        ln_fast<<<ROWS, 256, 0, stream>>>(h, (const float*)d_in[17] + i * D_,
                                          (const float*)d_in[18] + i * D_, ab1);
        gemm_mfma<<<dim3(DFF_ / 128, ROWS / 128), 256, 0, stream>>>(
            ab1, w1 + (size_t)i * D_ * DFF_, (const float*)d_in[20] + i * DFF_,
            nullptr, nullptr, ffnb, ROWS, DFF_, D_, 1);
        gemm_mfma<<<dim3(D_ / 128, ROWS / 128), 256, 0, stream>>>(
            ffnb, w2 + (size_t)i * DFF_ * D_, (const float*)d_in[22] + i * D_,
            h, h, nullptr, ROWS, D_, DFF_, 0);
    }

    // ---- heads ----
    heads_naive<<<B_ * T_, 256, 0, stream>>>(h,
        (const float*)d_in[23], (const float*)d_in[24],
        (const float*)d_in[25], (const float*)d_in[26],
        (const float*)d_in[27], (const float*)d_in[28], (float*)d_out);
}

// Round 6
// 2493.178 us; speedup vs baseline: 42.4086x; 1.8373x over previous
//
#include <hip/hip_runtime.h>
#include <hip/hip_bf16.h>
#include <math.h>

typedef unsigned short ushort_t;
typedef __attribute__((ext_vector_type(8))) short bf16x8;
typedef __attribute__((ext_vector_type(4))) float floatx4;

#define B_   8
#define T_   32
#define C_   4
#define HW_  84
#define P_   14
#define GP_  6
#define LOBS 36
#define S_   39
#define L_   (T_ * S_)          // 1248
#define D_   512
#define NH_  8
#define DH_  64
#define NL_  6
#define DFF_ 2048
#define NRET 120
#define NACT 18
#define NREW 3

#define ROWS (B_ * L_)          // 9984
#define OBS_ROWS (B_ * T_ * LOBS) // 9216
#define PK   (C_ * P_ * P_)     // 784
#define PKP  800                 // PK padded to %32

// workspace layout (float units)
#define OFF_H     0                         // fp32 9984*512
#define OFF_AB1   5111808                   // bf16 9984*512  (2,555,904 floats)
#define OFF_AB2   (OFF_AB1 + 2555904)
#define OFF_QKVB  (OFF_AB2 + 2555904)       // bf16 9984*1536 (7,667,712 floats)
#define OFF_FFNB  (OFF_QKVB + 7667712)      // bf16 9984*2048 (10,223,616 floats)
#define OFF_WB    (OFF_FFNB + 10223616)     // bf16 weights (9,641,984 floats)
#define WS_FLOATS (OFF_WB + 9641984 + 16)

static __device__ __forceinline__ float b2f_u(ushort_t u) {
    union { unsigned int u32; float f; } v; v.u32 = ((unsigned int)u) << 16; return v.f;
}
static __device__ __forceinline__ ushort_t f2b(float x) {
    union { float f; unsigned int u; } v; v.f = x;
    unsigned int r = v.u + 0x7FFFu + ((v.u >> 16) & 1u);
    return (ushort_t)(r >> 16);
}

__global__ void sentinel_kernel(float* out, int n) {
    int i = blockIdx.x * 256 + threadIdx.x;
    if (i < n) out[i] = 100.0f;
}

// ---------------- fp32 -> bf16 weight conversion ----------------
__global__ void cvt_kernel(const float* __restrict__ src, ushort_t* __restrict__ dst, int n) {
    int i = blockIdx.x * 256 + threadIdx.x;
    if (i < n) dst[i] = f2b(src[i]);
}

__global__ void cvt_patchw_kernel(const float* __restrict__ src, ushort_t* __restrict__ dst) {
    int i = blockIdx.x * 256 + threadIdx.x;
    if (i >= PKP * D_) return;
    int r = i / D_;
    dst[i] = (r < PK) ? f2b(src[i]) : (ushort_t)0;
}

// ---------------- patchify: frames fp32 -> Xp bf16 (9216 x 800) ----------------
__global__ void patchify_kernel(const float* __restrict__ frames, ushort_t* __restrict__ Xp) {
    int idx = blockIdx.x * 256 + threadIdx.x;
    if (idx >= OBS_ROWS * PKP) return;
    int r = idx / PKP, c = idx % PKP;
    if (c >= PK) { Xp[idx] = 0; return; }
    int bt = r / LOBS, p = r % LOBS;
    int gy = p / GP_, gx = p % GP_;
    int ch = c / (P_ * P_), rem = c % (P_ * P_);
    int py = rem / P_, px = rem % P_;
    size_t src = (((size_t)bt * C_ + ch) * HW_ + gy * P_ + py) * HW_ + gx * P_ + px;
    Xp[idx] = f2b(frames[src]);
}

// ---------------- MFMA bf16 GEMM: 128x128 tile, BK=32 (verified round 5) ------------
__global__ __launch_bounds__(256) void gemm_mfma(
    const ushort_t* __restrict__ A, const ushort_t* __restrict__ Bw,
    const float* __restrict__ bias, const float* __restrict__ residual,
    float* __restrict__ Cf, ushort_t* __restrict__ Cb,
    int M, int N, int K, int do_gelu)
{
    __shared__ ushort_t As[128 * 40];
    __shared__ ushort_t Bs[128 * 40];
    int t = threadIdx.x;
    int lane = t & 63, w = t >> 6;
    int row0 = blockIdx.y * 128, col0 = blockIdx.x * 128;
    int moff = (w & 1) << 6, noff = (w >> 1) << 6;
    int fr = lane & 15, fk = (lane >> 4) << 3;
    floatx4 acc[4][4];
#pragma unroll
    for (int i = 0; i < 4; ++i)
#pragma unroll
        for (int j = 0; j < 4; ++j) acc[i][j] = (floatx4){0.f, 0.f, 0.f, 0.f};
    int ar = t >> 2, akc = (t & 3) << 3;
    int bn = t & 127, bkh = (t >> 7) << 4;
    for (int k0 = 0; k0 < K; k0 += 32) {
#pragma unroll
        for (int rr = 0; rr < 128; rr += 64)
            *(bf16x8*)&As[(rr + ar) * 40 + akc] =
                *(const bf16x8*)(A + (size_t)(row0 + rr + ar) * K + k0 + akc);
        ushort_t tmp[16];
#pragma unroll
        for (int j = 0; j < 16; ++j)
            tmp[j] = Bw[(size_t)(k0 + bkh + j) * N + col0 + bn];
        *(bf16x8*)&Bs[bn * 40 + bkh] = *(bf16x8*)&tmp[0];
        *(bf16x8*)&Bs[bn * 40 + bkh + 8] = *(bf16x8*)&tmp[8];
        __syncthreads();
        bf16x8 af[4], bfr[4];
#pragma unroll
        for (int i = 0; i < 4; ++i)
            af[i] = *(const bf16x8*)&As[(moff + i * 16 + fr) * 40 + fk];
#pragma unroll
        for (int j = 0; j < 4; ++j)
            bfr[j] = *(const bf16x8*)&Bs[(noff + j * 16 + fr) * 40 + fk];
#pragma unroll
        for (int i = 0; i < 4; ++i)
#pragma unroll
            for (int j = 0; j < 4; ++j)
                acc[i][j] = __builtin_amdgcn_mfma_f32_16x16x32_bf16(af[i], bfr[j], acc[i][j], 0, 0, 0);
        __syncthreads();
    }
    int rquad = (lane >> 4) << 2;
#pragma unroll
    for (int j = 0; j < 4; ++j) {
        int col = col0 + noff + j * 16 + fr;
        float bv = bias ? bias[col] : 0.0f;
#pragma unroll
        for (int i = 0; i < 4; ++i) {
#pragma unroll
            for (int r = 0; r < 4; ++r) {
                int row = row0 + moff + i * 16 + rquad + r;
                float v = acc[i][j][r] + bv;
                if (do_gelu) v = 0.5f * v * (1.0f + erff(v * 0.70710678118654752f));
                if (residual) v += residual[(size_t)row * N + col];
                if (Cf) Cf[(size_t)row * N + col] = v;
                if (Cb) Cb[(size_t)row * N + col] = f2b(v);
            }
        }
    }
}

// ---------------- assemble tokens + embeddings -> h fp32 ----------------
__global__ void assemble_kernel(const float* __restrict__ obs,
                                const int* __restrict__ rtg,
                                const int* __restrict__ act,
                                const int* __restrict__ rew,
                                const float* __restrict__ retE,
                                const float* __restrict__ actE,
                                const float* __restrict__ rewE,
                                const float* __restrict__ posE,
                                const float* __restrict__ typeE,
                                float* __restrict__ h) {
    int idx = blockIdx.x * 256 + threadIdx.x;
    if (idx >= ROWS * D_) return;
    int d = idx & (D_ - 1);
    int bl = idx / D_;
    int l = bl % L_, b = bl / L_;
    int t = l / S_, off = l % S_;
    int bt = b * T_ + t;
    float v;
    int ty;
    if (off < LOBS) {
        v = obs[((size_t)bt * LOBS + off) * D_ + d];
        ty = 0;
    } else if (off == LOBS) {
        v = retE[(size_t)rtg[bt] * D_ + d];
        ty = 1;
    } else if (off == LOBS + 1) {
        v = actE[(size_t)act[bt] * D_ + d];
        ty = 2;
    } else {
        v = rewE[(size_t)rew[bt] * D_ + d];
        ty = 3;
    }
    v += posE[(size_t)l * D_ + d] + typeE[(size_t)ty * D_ + d];
    h[idx] = v;
}

// ---------------- LayerNorm fp32 in -> bf16 out ----------------
__global__ __launch_bounds__(256) void ln_fast(const float* __restrict__ x,
                                               const float* __restrict__ g,
                                               const float* __restrict__ bb,
                                               ushort_t* __restrict__ y) {
    int row = blockIdx.x;
    const float* xr = x + (size_t)row * D_;
    ushort_t* yr = y + (size_t)row * D_;
    int tid = threadIdx.x;
    float v0 = xr[tid], v1 = xr[tid + 256];
    __shared__ float red[4];
    int lane = tid & 63, wid = tid >> 6;
    float s = v0 + v1;
#pragma unroll
    for (int off = 32; off > 0; off >>= 1) s += __shfl_down(s, off, 64);
    if (lane == 0) red[wid] = s;
    __syncthreads();
    float mean = (red[0] + red[1] + red[2] + red[3]) * (1.0f / 512.0f);
    __syncthreads();
    float d0 = v0 - mean, d1 = v1 - mean;
    float vs = d0 * d0 + d1 * d1;
#pragma unroll
    for (int off = 32; off > 0; off >>= 1) vs += __shfl_down(vs, off, 64);
    if (lane == 0) red[wid] = vs;
    __syncthreads();
    float var = (red[0] + red[1] + red[2] + red[3]) * (1.0f / 512.0f);
    float rstd = rsqrtf(var + 1e-5f);
    yr[tid]       = f2b(d0 * rstd * g[tid]       + bb[tid]);
    yr[tid + 256] = f2b(d1 * rstd * g[tid + 256] + bb[tid + 256]);
}

// ---------------- MFMA flash attention: block = (64-q tile, head, batch) ----------------
// qkvb: [b][l][1536] bf16 (Q|K|V). out: [b][l][512] bf16.
// Fragment pattern identical to gemm_mfma (verified): operands read [idx16][quad*8+j]
// from k-contiguous LDS; C/D: col=lane&15, row=quad*4+reg.
__global__ __launch_bounds__(256) void attn_mfma(const ushort_t* __restrict__ qkvb,
                                                 ushort_t* __restrict__ outb)
{
    int qt = blockIdx.x, hh = blockIdx.y, b = blockIdx.z;
    int q0 = qt << 6;
    int t = threadIdx.x, lane = t & 63, w = t >> 6;
    int quad = lane >> 4, l16 = lane & 15;
    __shared__ ushort_t Qs[64][72];
    __shared__ ushort_t Ks[64][72];
    __shared__ ushort_t Vt[64][72];   // [d][k], col swizzled by ((d>>4)&3)<<3
    __shared__ ushort_t Ps[64][72];   // [q][k]
    const ushort_t* base = qkvb + (size_t)b * (L_ * 1536);
    int sr = t >> 2, scc = (t & 3) << 4;
    // stage Q tile
    {
        int qrow = q0 + sr; if (qrow >= L_) qrow = L_ - 1;
        const ushort_t* qp = base + (size_t)qrow * 1536 + hh * 64 + scc;
        *(bf16x8*)&Qs[sr][scc]     = *(const bf16x8*)qp;
        *(bf16x8*)&Qs[sr][scc + 8] = *(const bf16x8*)(qp + 8);
    }
    __syncthreads();
    bf16x8 aq0 = *(const bf16x8*)&Qs[w * 16 + l16][quad * 8];
    bf16x8 aq1 = *(const bf16x8*)&Qs[w * 16 + l16][quad * 8 + 32];

    int qg[4], stepq[4], obsq[4];
#pragma unroll
    for (int r = 0; r < 4; ++r) {
        qg[r] = q0 + w * 16 + quad * 4 + r;
        stepq[r] = qg[r] / S_;
        int offq = qg[r] - stepq[r] * S_;
        obsq[r] = offq < LOBS;
    }
    int qlast = q0 + 63; if (qlast > L_ - 1) qlast = L_ - 1;
    int kend_max = qlast;
    int we = (qlast / S_) * S_ + LOBS - 1;
    if (we > kend_max) kend_max = we;
    int ntiles = (kend_max >> 6) + 1;

    float m_run[4], l_run[4];
    floatx4 O[4];
#pragma unroll
    for (int r = 0; r < 4; ++r) { m_run[r] = -3.0e38f; l_run[r] = 0.0f; }
#pragma unroll
    for (int nb = 0; nb < 4; ++nb) O[nb] = (floatx4){0.f, 0.f, 0.f, 0.f};

    for (int kt = 0; kt < ntiles; ++kt) {
        int k0 = kt << 6;
        // stage K [k][d] and V transposed [d][k] (swizzled)
        {
            int krow = k0 + sr; if (krow >= L_) krow = L_ - 1;
            const ushort_t* kp = base + (size_t)krow * 1536 + 512 + hh * 64 + scc;
            const ushort_t* vp = base + (size_t)krow * 1536 + 1024 + hh * 64 + scc;
            *(bf16x8*)&Ks[sr][scc]     = *(const bf16x8*)kp;
            *(bf16x8*)&Ks[sr][scc + 8] = *(const bf16x8*)(kp + 8);
            bf16x8 v0 = *(const bf16x8*)vp, v1 = *(const bf16x8*)(vp + 8);
            int x = ((scc >> 4) & 3) << 3;   // swizzle const for this thread's d range
#pragma unroll
            for (int j = 0; j < 8; ++j) {
                Vt[scc + j][sr ^ x]     = ((ushort_t*)&v0)[j];
                Vt[scc + 8 + j][sr ^ x] = ((ushort_t*)&v1)[j];
            }
        }
        __syncthreads();
        // S = Q K^T for this tile (wave w owns q rows 16w..16w+16, all 64 k)
        floatx4 sc4[4];
#pragma unroll
        for (int nb = 0; nb < 4; ++nb) {
            sc4[nb] = (floatx4){0.f, 0.f, 0.f, 0.f};
            bf16x8 bk0 = *(const bf16x8*)&Ks[nb * 16 + l16][quad * 8];
            bf16x8 bk1 = *(const bf16x8*)&Ks[nb * 16 + l16][quad * 8 + 32];
            sc4[nb] = __builtin_amdgcn_mfma_f32_16x16x32_bf16(aq0, bk0, sc4[nb], 0, 0, 0);
            sc4[nb] = __builtin_amdgcn_mfma_f32_16x16x32_bf16(aq1, bk1, sc4[nb], 0, 0, 0);
        }
        // mask + scale + tile row-max (row stats live across the 16-lane column group)
        float mrow[4] = {-3.0e38f, -3.0e38f, -3.0e38f, -3.0e38f};
#pragma unroll
        for (int nb = 0; nb < 4; ++nb) {
            int kg = k0 + nb * 16 + l16;
            int stepk = kg / S_;
            int offk = kg - stepk * S_;
            int kobs = offk < LOBS;
#pragma unroll
            for (int r = 0; r < 4; ++r) {
                float s = sc4[nb][r] * 0.125f;
                int allowed = (kg <= qg[r]) || (obsq[r] && kobs && (stepk == stepq[r]));
                s = allowed ? s : -1.0e9f;
                sc4[nb][r] = s;
                mrow[r] = fmaxf(mrow[r], s);
            }
        }
#pragma unroll
        for (int off = 1; off < 16; off <<= 1)
#pragma unroll
            for (int r = 0; r < 4; ++r)
                mrow[r] = fmaxf(mrow[r], __shfl_xor(mrow[r], off, 64));
        float alpha[4], psum[4];
#pragma unroll
        for (int r = 0; r < 4; ++r) {
            float mnew = fmaxf(m_run[r], mrow[r]);
            alpha[r] = __expf(m_run[r] - mnew);
            m_run[r] = mnew;
            psum[r] = 0.0f;
        }
#pragma unroll
        for (int nb = 0; nb < 4; ++nb) {
#pragma unroll
            for (int r = 0; r < 4; ++r) {
                float p = __expf(sc4[nb][r] - m_run[r]);
                psum[r] += p;
                Ps[w * 16 + quad * 4 + r][nb * 16 + l16] = f2b(p);
            }
        }
#pragma unroll
        for (int off = 1; off < 16; off <<= 1)
#pragma unroll
            for (int r = 0; r < 4; ++r)
                psum[r] += __shfl_xor(psum[r], off, 64);
#pragma unroll
        for (int r = 0; r < 4; ++r)
            l_run[r] = l_run[r] * alpha[r] + psum[r];
#pragma unroll
        for (int nb = 0; nb < 4; ++nb)
#pragma unroll
            for (int r = 0; r < 4; ++r)
                O[nb][r] *= alpha[r];
        // PV: Ps rows 16w.. are wave-local (write->read same wave, no barrier needed)
        bf16x8 ap0 = *(const bf16x8*)&Ps[w * 16 + l16][quad * 8];
        bf16x8 ap1 = *(const bf16x8*)&Ps[w * 16 + l16][quad * 8 + 32];
#pragma unroll
        for (int nb = 0; nb < 4; ++nb) {
            int cs = (quad * 8) ^ (nb << 3);   // unswizzle Vt
            bf16x8 bv0 = *(const bf16x8*)&Vt[nb * 16 + l16][cs];
            bf16x8 bv1 = *(const bf16x8*)&Vt[nb * 16 + l16][cs + 32];
            O[nb] = __builtin_amdgcn_mfma_f32_16x16x32_bf16(ap0, bv0, O[nb], 0, 0, 0);
            O[nb] = __builtin_amdgcn_mfma_f32_16x16x32_bf16(ap1, bv1, O[nb], 0, 0, 0);
        }
        __syncthreads();   // protect Ks/Vt against next tile's staging
    }
#pragma unroll
    for (int r = 0; r < 4; ++r) {
        if (qg[r] < L_) {
            float inv = 1.0f / l_run[r];
#pragma unroll
            for (int nb = 0; nb < 4; ++nb)
                outb[((size_t)b * L_ + qg[r]) * 512 + hh * 64 + nb * 16 + l16] =
                    f2b(O[nb][r] * inv);
        }
    }
}

// ---------------- heads: fp32 h + fp32 weights -> fp32 out ----------------
__global__ void heads_naive(const float* __restrict__ h,
                            const float* __restrict__ hW_ret, const float* __restrict__ hb_ret,
                            const float* __restrict__ hW_act, const float* __restrict__ hb_act,
                            const float* __restrict__ hW_rew, const float* __restrict__ hb_rew,
                            float* __restrict__ out) {
    int bt = blockIdx.x;
    int b = bt / T_, t = bt % T_;
    size_t base = ((size_t)b * L_ + (size_t)t * S_) * D_;
    const float* hr = h + base + (size_t)(LOBS - 1) * D_;
    const float* ha = h + base + (size_t)LOBS * D_;
    const float* hw = h + base + (size_t)(LOBS + 1) * D_;
    int tid = threadIdx.x;
    if (tid < NRET) {
        float acc = hb_ret[tid];
        for (int k = 0; k < D_; ++k) acc += hr[k] * hW_ret[(size_t)k * NRET + tid];
        out[(size_t)bt * NRET + tid] = acc;
    } else if (tid < NRET + NACT) {
        int n = tid - NRET;
        float acc = hb_act[n];
        for (int k = 0; k < D_; ++k) acc += ha[k] * hW_act[(size_t)k * NACT + n];
        out[(size_t)(B_ * T_ * NRET) + (size_t)bt * NACT + n] = acc;
    } else if (tid < NRET + NACT + NREW) {
        int n = tid - NRET - NACT;
        float acc = hb_rew[n];
        for (int k = 0; k < D_; ++k) acc += hw[k] * hW_rew[(size_t)k * NREW + n];
        out[(size_t)(B_ * T_ * (NRET + NACT)) + (size_t)bt * NREW + n] = acc;
    }
}

static inline int cdiv_i(long long a, int b) { return (int)((a + b - 1) / b); }

extern "C" void kernel_launch(void* const* d_in, const int* in_sizes, int n_in,
                              void* d_out, int out_size, void* d_ws, size_t ws_size,
                              hipStream_t stream) {
    if (ws_size < (size_t)WS_FLOATS * sizeof(float)) {
        sentinel_kernel<<<(out_size + 255) / 256, 256, 0, stream>>>((float*)d_out, out_size);
        return;
    }
    const float* frames  = (const float*)d_in[0];
    const int*   rtg     = (const int*)d_in[1];
    const int*   actions = (const int*)d_in[2];
    const int*   rewards = (const int*)d_in[3];

    float* ws   = (float*)d_ws;
    float* h    = ws + OFF_H;
    ushort_t* ab1  = (ushort_t*)(ws + OFF_AB1);
    ushort_t* ab2  = (ushort_t*)(ws + OFF_AB2);
    ushort_t* qkvb = (ushort_t*)(ws + OFF_QKVB);
    ushort_t* ffnb = (ushort_t*)(ws + OFF_FFNB);
    ushort_t* xpb  = (ushort_t*)(ws + OFF_FFNB);                 // alias (pre-loop)
    float*    obs  = ws + OFF_FFNB + 3686400;                    // alias (pre-loop)
    ushort_t* wpatch = (ushort_t*)(ws + OFF_WB);
    ushort_t* wqkv = wpatch + PKP * D_;
    ushort_t* wo   = wqkv + NL_ * D_ * 3 * D_;
    ushort_t* w1   = wo + NL_ * D_ * D_;
    ushort_t* w2   = w1 + NL_ * D_ * DFF_;

    // ---- weight conversion fp32 -> bf16 ----
    cvt_patchw_kernel<<<cdiv_i(PKP * D_, 256), 256, 0, stream>>>((const float*)d_in[4], wpatch);
    cvt_kernel<<<cdiv_i(NL_ * D_ * 3 * D_, 256), 256, 0, stream>>>((const float*)d_in[11], wqkv, NL_ * D_ * 3 * D_);
    cvt_kernel<<<cdiv_i(NL_ * D_ * D_, 256), 256, 0, stream>>>((const float*)d_in[13], wo, NL_ * D_ * D_);
    cvt_kernel<<<cdiv_i(NL_ * D_ * DFF_, 256), 256, 0, stream>>>((const float*)d_in[19], w1, NL_ * D_ * DFF_);
    cvt_kernel<<<cdiv_i(NL_ * DFF_ * D_, 256), 256, 0, stream>>>((const float*)d_in[21], w2, NL_ * DFF_ * D_);

    // ---- patchify + patch embed ----
    patchify_kernel<<<cdiv_i((long long)OBS_ROWS * PKP, 256), 256, 0, stream>>>(frames, xpb);
    gemm_mfma<<<dim3(D_ / 128, OBS_ROWS / 128), 256, 0, stream>>>(
        xpb, wpatch, (const float*)d_in[5], nullptr, obs, nullptr, OBS_ROWS, D_, PKP, 0);

    // ---- assemble sequence ----
    assemble_kernel<<<cdiv_i((long long)ROWS * D_, 256), 256, 0, stream>>>(
        obs, rtg, actions, rewards,
        (const float*)d_in[6], (const float*)d_in[7], (const float*)d_in[8],
        (const float*)d_in[9], (const float*)d_in[10], h);

    // ---- transformer layers ----
    for (int i = 0; i < NL_; ++i) {
        ln_fast<<<ROWS, 256, 0, stream>>>(h, (const float*)d_in[15] + i * D_,
                                          (const float*)d_in[16] + i * D_, ab1);
        gemm_mfma<<<dim3(3 * D_ / 128, ROWS / 128), 256, 0, stream>>>(
            ab1, wqkv + (size_t)i * D_ * 3 * D_, (const float*)d_in[12] + i * 3 * D_,
            nullptr, nullptr, qkvb, ROWS, 3 * D_, D_, 0);
        attn_mfma<<<dim3((L_ + 63) / 64, NH_, B_), 256, 0, stream>>>(qkvb, ab2);
        gemm_mfma<<<dim3(D_ / 128, ROWS / 128), 256, 0, stream>>>(
            ab2, wo + (size_t)i * D_ * D_, (const float*)d_in[14] + i * D_,
            h, h, nullptr, ROWS, D_, D_, 0);
        ln_fast<<<ROWS, 256, 0, stream>>>(h, (const float*)d_in[17] + i * D_,
                                          (const float*)d_in[18] + i * D_, ab1);
        gemm_mfma<<<dim3(DFF_ / 128, ROWS / 128), 256, 0, stream>>>(
            ab1, w1 + (size_t)i * D_ * DFF_, (const float*)d_in[20] + i * DFF_,
            nullptr, nullptr, ffnb, ROWS, DFF_, D_, 1);
        gemm_mfma<<<dim3(D_ / 128, ROWS / 128), 256, 0, stream>>>(
            ffnb, w2 + (size_t)i * DFF_ * D_, (const float*)d_in[22] + i * D_,
            h, h, nullptr, ROWS, D_, DFF_, 0);
    }

    // ---- heads ----
    heads_naive<<<B_ * T_, 256, 0, stream>>>(h,
        (const float*)d_in[23], (const float*)d_in[24],
        (const float*)d_in[25], (const float*)d_in[26],
        (const float*)d_in[27], (const float*)d_in[28], (float*)d_out);
}

// Round 7
// 2262.761 us; speedup vs baseline: 46.7270x; 1.1018x over previous
//
#include <hip/hip_runtime.h>
#include <hip/hip_bf16.h>
#include <math.h>

typedef unsigned short ushort_t;
typedef __attribute__((ext_vector_type(8))) short bf16x8;
typedef __attribute__((ext_vector_type(4))) float floatx4;

#define B_   8
#define T_   32
#define C_   4
#define HW_  84
#define P_   14
#define GP_  6
#define LOBS 36
#define S_   39
#define L_   (T_ * S_)          // 1248
#define D_   512
#define NH_  8
#define DH_  64
#define NL_  6
#define DFF_ 2048
#define NRET 120
#define NACT 18
#define NREW 3

#define ROWS (B_ * L_)          // 9984
#define OBS_ROWS (B_ * T_ * LOBS) // 9216
#define PK   (C_ * P_ * P_)     // 784
#define PKP  800                 // PK padded to %32

// workspace layout (float units) — identical totals to round 5/6
#define OFF_H     0                         // fp32 9984*512
#define OFF_AB1   5111808                   // bf16 9984*512
#define OFF_AB2   (OFF_AB1 + 2555904)
#define OFF_QKVB  (OFF_AB2 + 2555904)       // bf16 9984*1536
#define OFF_FFNB  (OFF_QKVB + 7667712)      // bf16 9984*2048 (aliased: VtG / Xp+obs)
#define OFF_WB    (OFF_FFNB + 10223616)     // bf16 transposed weights
#define WS_FLOATS (OFF_WB + 9641984 + 16)

static __device__ __forceinline__ ushort_t f2b(float x) {
    union { float f; unsigned int u; } v; v.f = x;
    unsigned int r = v.u + 0x7FFFu + ((v.u >> 16) & 1u);
    return (ushort_t)(r >> 16);
}

static __device__ __forceinline__ void gload16(const ushort_t* g, ushort_t* l) {
    __builtin_amdgcn_global_load_lds(
        (const __attribute__((address_space(1))) void*)g,
        (__attribute__((address_space(3))) void*)l, 16, 0, 0);
}

__global__ void sentinel_kernel(float* out, int n) {
    int i = blockIdx.x * 256 + threadIdx.x;
    if (i < n) out[i] = 100.0f;
}

// ---------------- weight transpose+convert: [K][N] fp32 -> [N][K] bf16, per layer -------
__global__ __launch_bounds__(256) void transpose_cvt_kernel(
    const float* __restrict__ src, ushort_t* __restrict__ dst, int K, int N)
{
    __shared__ float tile[32][33];
    int layer = blockIdx.z;
    int n0 = blockIdx.x * 32, k0 = blockIdx.y * 32;
    int tx = threadIdx.x & 31, ty = threadIdx.x >> 5;   // 32 x 8
    const float* s = src + (size_t)layer * K * N;
    ushort_t* d = dst + (size_t)layer * N * K;
#pragma unroll
    for (int r = 0; r < 32; r += 8)
        tile[ty + r][tx] = s[(size_t)(k0 + ty + r) * N + n0 + tx];
    __syncthreads();
#pragma unroll
    for (int r = 0; r < 32; r += 8)
        d[(size_t)(n0 + ty + r) * K + k0 + tx] = f2b(tile[tx][ty + r]);
}

// patch_W [784][512] fp32 -> [512][800] bf16 (k-pad zeros)
__global__ __launch_bounds__(256) void transpose_patchw_kernel(
    const float* __restrict__ src, ushort_t* __restrict__ dst)
{
    __shared__ float tile[32][33];
    int n0 = blockIdx.x * 32, k0 = blockIdx.y * 32;
    int tx = threadIdx.x & 31, ty = threadIdx.x >> 5;
#pragma unroll
    for (int r = 0; r < 32; r += 8) {
        int k = k0 + ty + r;
        tile[ty + r][tx] = (k < PK) ? src[(size_t)k * D_ + n0 + tx] : 0.0f;
    }
    __syncthreads();
#pragma unroll
    for (int r = 0; r < 32; r += 8)
        dst[(size_t)(n0 + ty + r) * PKP + k0 + tx] = f2b(tile[tx][ty + r]);
}

// ---------------- patchify: frames fp32 -> Xp bf16 (9216 x 800) ----------------
__global__ void patchify_kernel(const float* __restrict__ frames, ushort_t* __restrict__ Xp) {
    int idx = blockIdx.x * 256 + threadIdx.x;
    if (idx >= OBS_ROWS * PKP) return;
    int r = idx / PKP, c = idx % PKP;
    if (c >= PK) { Xp[idx] = 0; return; }
    int bt = r / LOBS, p = r % LOBS;
    int gy = p / GP_, gx = p % GP_;
    int ch = c / (P_ * P_), rem = c % (P_ * P_);
    int py = rem / P_, px = rem % P_;
    size_t src = (((size_t)bt * C_ + ch) * HW_ + gy * P_ + py) * HW_ + gx * P_ + px;
    Xp[idx] = f2b(frames[src]);
}

// ---------------- MFMA GEMM, global_load_lds staging (m97 structure) ----------------
// A: MxK bf16 row-major. BT: NxK bf16 row-major (pre-transposed weights).
// C = act(A@B + bias) [+residual]; out fp32 (Cf) and/or bf16 (Cb). M%128, N%128, K%32.
__global__ __launch_bounds__(256) void gemm_mfma(
    const ushort_t* __restrict__ A, const ushort_t* __restrict__ BT,
    const float* __restrict__ bias, const float* __restrict__ residual,
    float* __restrict__ Cf, ushort_t* __restrict__ Cb,
    int M, int N, int K, int do_gelu)
{
    __shared__ ushort_t As[128 * 32];
    __shared__ ushort_t Bs[128 * 32];
    int t = threadIdx.x, lane = t & 63, w = t >> 6;
    int row0 = blockIdx.y * 128, col0 = blockIdx.x * 128;
    int moff = (w & 1) << 6, noff = (w >> 1) << 6;
    int l16 = lane & 15, quad = lane >> 4;
    floatx4 acc[4][4];
#pragma unroll
    for (int i = 0; i < 4; ++i)
#pragma unroll
        for (int j = 0; j < 4; ++j) acc[i][j] = (floatx4){0.f, 0.f, 0.f, 0.f};
    // staging: 512 chunks of 16B per tile per matrix; wave w issues instrs 2w, 2w+1
    int n0i = (2 * w) * 64 + lane;
    int n1i = (2 * w + 1) * 64 + lane;
    const ushort_t* gA0 = A + (size_t)(row0 + (n0i >> 2)) * K + (n0i & 3) * 8;
    const ushort_t* gA1 = A + (size_t)(row0 + (n1i >> 2)) * K + (n1i & 3) * 8;
    const ushort_t* gB0 = BT + (size_t)(col0 + (n0i >> 2)) * K + (n0i & 3) * 8;
    const ushort_t* gB1 = BT + (size_t)(col0 + (n1i >> 2)) * K + (n1i & 3) * 8;
    ushort_t* lA0 = &As[(2 * w) * 512];       // wave-uniform LDS bases
    ushort_t* lA1 = &As[(2 * w + 1) * 512];
    ushort_t* lB0 = &Bs[(2 * w) * 512];
    ushort_t* lB1 = &Bs[(2 * w + 1) * 512];
    for (int k0 = 0; k0 < K; k0 += 32) {
        gload16(gA0, lA0);
        gload16(gA1, lA1);
        gload16(gB0, lB0);
        gload16(gB1, lB1);
        gA0 += 32; gA1 += 32; gB0 += 32; gB1 += 32;
        __syncthreads();
        bf16x8 af[4], bfv[4];
#pragma unroll
        for (int i = 0; i < 4; ++i)
            af[i] = *(const bf16x8*)&As[(moff + i * 16 + l16) * 32 + quad * 8];
#pragma unroll
        for (int j = 0; j < 4; ++j)
            bfv[j] = *(const bf16x8*)&Bs[(noff + j * 16 + l16) * 32 + quad * 8];
#pragma unroll
        for (int i = 0; i < 4; ++i)
#pragma unroll
            for (int j = 0; j < 4; ++j)
                acc[i][j] = __builtin_amdgcn_mfma_f32_16x16x32_bf16(af[i], bfv[j], acc[i][j], 0, 0, 0);
        __syncthreads();
    }
    // C/D layout (verified): col = lane&15, row = (lane>>4)*4 + reg
    int rquad = quad << 2;
#pragma unroll
    for (int j = 0; j < 4; ++j) {
        int col = col0 + noff + j * 16 + l16;
        float bv = bias ? bias[col] : 0.0f;
#pragma unroll
        for (int i = 0; i < 4; ++i) {
#pragma unroll
            for (int r = 0; r < 4; ++r) {
                int row = row0 + moff + i * 16 + rquad + r;
                float v = acc[i][j][r] + bv;
                if (do_gelu) v = 0.5f * v * (1.0f + erff(v * 0.70710678118654752f));
                if (residual) v += residual[(size_t)row * N + col];
                if (Cf) Cf[(size_t)row * N + col] = v;
                if (Cb) Cb[(size_t)row * N + col] = f2b(v);
            }
        }
    }
}

// ---------------- assemble tokens + embeddings -> h fp32 ----------------
__global__ void assemble_kernel(const float* __restrict__ obs,
                                const int* __restrict__ rtg,
                                const int* __restrict__ act,
                                const int* __restrict__ rew,
                                const float* __restrict__ retE,
                                const float* __restrict__ actE,
                                const float* __restrict__ rewE,
                                const float* __restrict__ posE,
                                const float* __restrict__ typeE,
                                float* __restrict__ h) {
    int idx = blockIdx.x * 256 + threadIdx.x;
    if (idx >= ROWS * D_) return;
    int d = idx & (D_ - 1);
    int bl = idx / D_;
    int l = bl % L_, b = bl / L_;
    int t = l / S_, off = l % S_;
    int bt = b * T_ + t;
    float v;
    int ty;
    if (off < LOBS) {
        v = obs[((size_t)bt * LOBS + off) * D_ + d];
        ty = 0;
    } else if (off == LOBS) {
        v = retE[(size_t)rtg[bt] * D_ + d];
        ty = 1;
    } else if (off == LOBS + 1) {
        v = actE[(size_t)act[bt] * D_ + d];
        ty = 2;
    } else {
        v = rewE[(size_t)rew[bt] * D_ + d];
        ty = 3;
    }
    v += posE[(size_t)l * D_ + d] + typeE[(size_t)ty * D_ + d];
    h[idx] = v;
}

// ---------------- LayerNorm fp32 in -> bf16 out ----------------
__global__ __launch_bounds__(256) void ln_fast(const float* __restrict__ x,
                                               const float* __restrict__ g,
                                               const float* __restrict__ bb,
                                               ushort_t* __restrict__ y) {
    int row = blockIdx.x;
    const float* xr = x + (size_t)row * D_;
    ushort_t* yr = y + (size_t)row * D_;
    int tid = threadIdx.x;
    float v0 = xr[tid], v1 = xr[tid + 256];
    __shared__ float red[4];
    int lane = tid & 63, wid = tid >> 6;
    float s = v0 + v1;
#pragma unroll
    for (int off = 32; off > 0; off >>= 1) s += __shfl_down(s, off, 64);
    if (lane == 0) red[wid] = s;
    __syncthreads();
    float mean = (red[0] + red[1] + red[2] + red[3]) * (1.0f / 512.0f);
    __syncthreads();
    float d0 = v0 - mean, d1 = v1 - mean;
    float vs = d0 * d0 + d1 * d1;
#pragma unroll
    for (int off = 32; off > 0; off >>= 1) vs += __shfl_down(vs, off, 64);
    if (lane == 0) red[wid] = vs;
    __syncthreads();
    float var = (red[0] + red[1] + red[2] + red[3]) * (1.0f / 512.0f);
    float rstd = rsqrtf(var + 1e-5f);
    yr[tid]       = f2b(d0 * rstd * g[tid]       + bb[tid]);
    yr[tid + 256] = f2b(d1 * rstd * g[tid + 256] + bb[tid + 256]);
}

// ---------------- V pre-transpose per layer: qkvb V -> VtG[bh][d][l] bf16 ------------
__global__ __launch_bounds__(256) void vt_prep(const ushort_t* __restrict__ qkvb,
                                               ushort_t* __restrict__ vtg)
{
    __shared__ ushort_t tl[32][33];
    int bh = blockIdx.z; int b = bh >> 3, hh = bh & 7;
    int l0 = blockIdx.x * 32, d0 = blockIdx.y * 32;
    int tx = threadIdx.x & 31, ty = threadIdx.x >> 5;
#pragma unroll
    for (int r = 0; r < 32; r += 8)
        tl[ty + r][tx] = qkvb[((size_t)b * L_ + l0 + ty + r) * 1536 + 1024 + hh * 64 + d0 + tx];
    __syncthreads();
#pragma unroll
    for (int r = 0; r < 32; r += 8)
        vtg[((size_t)bh * 64 + d0 + ty + r) * L_ + l0 + tx] = tl[tx][ty + r];
}

// ---------------- barrier-free MFMA flash attention, fixed-max softmax ----------------
// grid (bh=64, qt=20); block 256 (4 waves, each owns 16 q rows).
// K fragments direct from qkvb (K is [l][d] = B-operand layout); V fragments from VtG.
// Only P round-trips through a wave-private LDS slab -> NO __syncthreads in k-loop.
__global__ __launch_bounds__(256) void attn_mfma(const ushort_t* __restrict__ qkvb,
                                                 const ushort_t* __restrict__ vtg,
                                                 ushort_t* __restrict__ outb)
{
    int bh = blockIdx.x; int hh = bh & 7, b = bh >> 3;
    int qt = blockIdx.y;
    int q0 = qt << 6;
    int t = threadIdx.x, lane = t & 63, w = t >> 6;
    int l16 = lane & 15, quad = lane >> 4;
    __shared__ ushort_t Ps[64][72];
    const ushort_t* base = qkvb + (size_t)b * (L_ * 1536);
    const ushort_t* vbase = vtg + (size_t)bh * 64 * L_;
    // Q fragments in registers (A-operand: row=l16, k=quad*8+j)
    int qrow_l = q0 + w * 16 + l16; if (qrow_l >= L_) qrow_l = L_ - 1;
    const ushort_t* qp = base + (size_t)qrow_l * 1536 + hh * 64 + quad * 8;
    bf16x8 aq0 = *(const bf16x8*)qp;
    bf16x8 aq1 = *(const bf16x8*)(qp + 32);
    // C-layout q rows for this lane
    int qg[4], stepq[4], obsq[4];
#pragma unroll
    for (int r = 0; r < 4; ++r) {
        qg[r] = q0 + w * 16 + quad * 4 + r;
        stepq[r] = qg[r] / S_;
        obsq[r] = (qg[r] - stepq[r] * S_) < LOBS;
    }
    int qlast = q0 + 63; if (qlast > L_ - 1) qlast = L_ - 1;
    int kend_max = qlast;
    int we = (qlast / S_) * S_ + LOBS - 1;
    if (we > kend_max) kend_max = we;
    int ntiles = (kend_max >> 6) + 1;

    float psum[4] = {0.f, 0.f, 0.f, 0.f};
    floatx4 O[4];
#pragma unroll
    for (int nb = 0; nb < 4; ++nb) O[nb] = (floatx4){0.f, 0.f, 0.f, 0.f};

    for (int kt = 0; kt < ntiles; ++kt) {
        int k0 = kt << 6;
        // S = Q K^T : K fragments straight from global (B-operand: row=k(l16), k-dim=d)
        floatx4 sc4[4];
#pragma unroll
        for (int nb = 0; nb < 4; ++nb) {
            int krow = k0 + nb * 16 + l16; if (krow >= L_) krow = L_ - 1;
            const ushort_t* kp = base + (size_t)krow * 1536 + 512 + hh * 64 + quad * 8;
            bf16x8 bk0 = *(const bf16x8*)kp;
            bf16x8 bk1 = *(const bf16x8*)(kp + 32);
            floatx4 z = (floatx4){0.f, 0.f, 0.f, 0.f};
            z = __builtin_amdgcn_mfma_f32_16x16x32_bf16(aq0, bk0, z, 0, 0, 0);
            z = __builtin_amdgcn_mfma_f32_16x16x32_bf16(aq1, bk1, z, 0, 0, 0);
            sc4[nb] = z;
        }
        // P = exp(S/8) with mask; fixed-max softmax (scores are LN-bounded, no overflow)
        if (kt < qt) {   // tile fully causal-allowed
#pragma unroll
            for (int nb = 0; nb < 4; ++nb)
#pragma unroll
                for (int r = 0; r < 4; ++r) {
                    float p = __expf(sc4[nb][r] * 0.125f);
                    psum[r] += p;
                    Ps[w * 16 + quad * 4 + r][nb * 16 + l16] = f2b(p);
                }
        } else {
#pragma unroll
            for (int nb = 0; nb < 4; ++nb) {
                int kg = k0 + nb * 16 + l16;
                int stepk = kg / S_;
                int kobs = (kg - stepk * S_) < LOBS;
#pragma unroll
                for (int r = 0; r < 4; ++r) {
                    int allowed = (kg <= qg[r]) || (obsq[r] && kobs && (stepk == stepq[r]));
                    float p = allowed ? __expf(sc4[nb][r] * 0.125f) : 0.0f;
                    psum[r] += p;
                    Ps[w * 16 + quad * 4 + r][nb * 16 + l16] = f2b(p);
                }
            }
        }
        // PV : P from wave-private LDS slab, V^T fragments straight from VtG
        bf16x8 ap0 = *(const bf16x8*)&Ps[w * 16 + l16][quad * 8];
        bf16x8 ap1 = *(const bf16x8*)&Ps[w * 16 + l16][quad * 8 + 32];
        int c0 = k0 + quad * 8;      if (c0 > L_ - 8) c0 = L_ - 8;   // clamp: masked P=0 kills
        int c1 = k0 + 32 + quad * 8; if (c1 > L_ - 8) c1 = L_ - 8;
#pragma unroll
        for (int nb = 0; nb < 4; ++nb) {
            const ushort_t* vp = vbase + (size_t)(nb * 16 + l16) * L_;
            bf16x8 bv0 = *(const bf16x8*)(vp + c0);
            bf16x8 bv1 = *(const bf16x8*)(vp + c1);
            O[nb] = __builtin_amdgcn_mfma_f32_16x16x32_bf16(ap0, bv0, O[nb], 0, 0, 0);
            O[nb] = __builtin_amdgcn_mfma_f32_16x16x32_bf16(ap1, bv1, O[nb], 0, 0, 0);
        }
    }
    // final row-sum reduce across the 16-lane column group
#pragma unroll
    for (int off = 1; off < 16; off <<= 1)
#pragma unroll
        for (int r = 0; r < 4; ++r)
            psum[r] += __shfl_xor(psum[r], off, 64);
#pragma unroll
    for (int r = 0; r < 4; ++r) {
        if (qg[r] < L_) {
            float inv = 1.0f / psum[r];
#pragma unroll
            for (int nb = 0; nb < 4; ++nb)
                outb[((size_t)b * L_ + qg[r]) * 512 + hh * 64 + nb * 16 + l16] =
                    f2b(O[nb][r] * inv);
        }
    }
}

// ---------------- heads: fp32 h + fp32 weights -> fp32 out ----------------
__global__ void heads_naive(const float* __restrict__ h,
                            const float* __restrict__ hW_ret, const float* __restrict__ hb_ret,
                            const float* __restrict__ hW_act, const float* __restrict__ hb_act,
                            const float* __restrict__ hW_rew, const float* __restrict__ hb_rew,
                            float* __restrict__ out) {
    int bt = blockIdx.x;
    int b = bt / T_, t = bt % T_;
    size_t base = ((size_t)b * L_ + (size_t)t * S_) * D_;
    const float* hr = h + base + (size_t)(LOBS - 1) * D_;
    const float* ha = h + base + (size_t)LOBS * D_;
    const float* hw = h + base + (size_t)(LOBS + 1) * D_;
    int tid = threadIdx.x;
    if (tid < NRET) {
        float acc = hb_ret[tid];
        for (int k = 0; k < D_; ++k) acc += hr[k] * hW_ret[(size_t)k * NRET + tid];
        out[(size_t)bt * NRET + tid] = acc;
    } else if (tid < NRET + NACT) {
        int n = tid - NRET;
        float acc = hb_act[n];
        for (int k = 0; k < D_; ++k) acc += ha[k] * hW_act[(size_t)k * NACT + n];
        out[(size_t)(B_ * T_ * NRET) + (size_t)bt * NACT + n] = acc;
    } else if (tid < NRET + NACT + NREW) {
        int n = tid - NRET - NACT;
        float acc = hb_rew[n];
        for (int k = 0; k < D_; ++k) acc += hw[k] * hW_rew[(size_t)k * NREW + n];
        out[(size_t)(B_ * T_ * (NRET + NACT)) + (size_t)bt * NREW + n] = acc;
    }
}

static inline int cdiv_i(long long a, int b) { return (int)((a + b - 1) / b); }

extern "C" void kernel_launch(void* const* d_in, const int* in_sizes, int n_in,
                              void* d_out, int out_size, void* d_ws, size_t ws_size,
                              hipStream_t stream) {
    if (ws_size < (size_t)WS_FLOATS * sizeof(float)) {
        sentinel_kernel<<<(out_size + 255) / 256, 256, 0, stream>>>((float*)d_out, out_size);
        return;
    }
    const float* frames  = (const float*)d_in[0];
    const int*   rtg     = (const int*)d_in[1];
    const int*   actions = (const int*)d_in[2];
    const int*   rewards = (const int*)d_in[3];

    float* ws   = (float*)d_ws;
    float* h    = ws + OFF_H;
    ushort_t* ab1  = (ushort_t*)(ws + OFF_AB1);
    ushort_t* ab2  = (ushort_t*)(ws + OFF_AB2);
    ushort_t* qkvb = (ushort_t*)(ws + OFF_QKVB);
    ushort_t* ffnb = (ushort_t*)(ws + OFF_FFNB);
    ushort_t* vtg  = (ushort_t*)(ws + OFF_FFNB);                 // alias (attn phase)
    ushort_t* xpb  = (ushort_t*)(ws + OFF_FFNB);                 // alias (pre-loop)
    float*    obs  = ws + OFF_FFNB + 3686400;                    // alias (pre-loop)
    ushort_t* wpatchT = (ushort_t*)(ws + OFF_WB);                // [512][800]
    ushort_t* wqkvT = wpatchT + PKP * D_;                        // [6][1536][512]
    ushort_t* woT   = wqkvT + NL_ * D_ * 3 * D_;                 // [6][512][512]
    ushort_t* w1T   = woT + NL_ * D_ * D_;                       // [6][2048][512]
    ushort_t* w2T   = w1T + NL_ * D_ * DFF_;                     // [6][512][2048]

    // ---- weight transpose + fp32->bf16 ----
    transpose_patchw_kernel<<<dim3(16, 25), 256, 0, stream>>>((const float*)d_in[4], wpatchT);
    transpose_cvt_kernel<<<dim3(48, 16, NL_), 256, 0, stream>>>((const float*)d_in[11], wqkvT, D_, 3 * D_);
    transpose_cvt_kernel<<<dim3(16, 16, NL_), 256, 0, stream>>>((const float*)d_in[13], woT, D_, D_);
    transpose_cvt_kernel<<<dim3(64, 16, NL_), 256, 0, stream>>>((const float*)d_in[19], w1T, D_, DFF_);
    transpose_cvt_kernel<<<dim3(16, 64, NL_), 256, 0, stream>>>((const float*)d_in[21], w2T, DFF_, D_);

    // ---- patchify + patch embed ----
    patchify_kernel<<<cdiv_i((long long)OBS_ROWS * PKP, 256), 256, 0, stream>>>(frames, xpb);
    gemm_mfma<<<dim3(D_ / 128, OBS_ROWS / 128), 256, 0, stream>>>(
        xpb, wpatchT, (const float*)d_in[5], nullptr, obs, nullptr, OBS_ROWS, D_, PKP, 0);

    // ---- assemble sequence ----
    assemble_kernel<<<cdiv_i((long long)ROWS * D_, 256), 256, 0, stream>>>(
        obs, rtg, actions, rewards,
        (const float*)d_in[6], (const float*)d_in[7], (const float*)d_in[8],
        (const float*)d_in[9], (const float*)d_in[10], h);

    // ---- transformer layers ----
    for (int i = 0; i < NL_; ++i) {
        ln_fast<<<ROWS, 256, 0, stream>>>(h, (const float*)d_in[15] + i * D_,
                                          (const float*)d_in[16] + i * D_, ab1);
        gemm_mfma<<<dim3(3 * D_ / 128, ROWS / 128), 256, 0, stream>>>(
            ab1, wqkvT + (size_t)i * D_ * 3 * D_, (const float*)d_in[12] + i * 3 * D_,
            nullptr, nullptr, qkvb, ROWS, 3 * D_, D_, 0);
        vt_prep<<<dim3(39, 2, 64), 256, 0, stream>>>(qkvb, vtg);
        attn_mfma<<<dim3(64, 20), 256, 0, stream>>>(qkvb, vtg, ab2);
        gemm_mfma<<<dim3(D_ / 128, ROWS / 128), 256, 0, stream>>>(
            ab2, woT + (size_t)i * D_ * D_, (const float*)d_in[14] + i * D_,
            h, h, nullptr, ROWS, D_, D_, 0);
        ln_fast<<<ROWS, 256, 0, stream>>>(h, (const float*)d_in[17] + i * D_,
                                          (const float*)d_in[18] + i * D_, ab1);
        gemm_mfma<<<dim3(DFF_ / 128, ROWS / 128), 256, 0, stream>>>(
            ab1, w1T + (size_t)i * D_ * DFF_, (const float*)d_in[20] + i * DFF_,
            nullptr, nullptr, ffnb, ROWS, DFF_, D_, 1);
        gemm_mfma<<<dim3(D_ / 128, ROWS / 128), 256, 0, stream>>>(
            ffnb, w2T + (size_t)i * DFF_ * D_, (const float*)d_in[22] + i * D_,
            h, h, nullptr, ROWS, D_, DFF_, 0);
    }

    // ---- heads ----
    heads_naive<<<B_ * T_, 256, 0, stream>>>(h,
        (const float*)d_in[23], (const float*)d_in[24],
        (const float*)d_in[25], (const float*)d_in[26],
        (const float*)d_in[27], (const float*)d_in[28], (float*)d_out);
}

// Round 8
// 2135.780 us; speedup vs baseline: 49.5051x; 1.0595x over previous
//
#include <hip/hip_runtime.h>
#include <hip/hip_bf16.h>
#include <math.h>

typedef unsigned short ushort_t;
typedef __attribute__((ext_vector_type(8))) short bf16x8;
typedef __attribute__((ext_vector_type(4))) float floatx4;

#define B_   8
#define T_   32
#define C_   4
#define HW_  84
#define P_   14
#define GP_  6
#define LOBS 36
#define S_   39
#define L_   (T_ * S_)          // 1248
#define D_   512
#define NH_  8
#define DH_  64
#define NL_  6
#define DFF_ 2048
#define NRET 120
#define NACT 18
#define NREW 3

#define ROWS (B_ * L_)          // 9984
#define OBS_ROWS (B_ * T_ * LOBS) // 9216
#define PK   (C_ * P_ * P_)     // 784
#define PKP  800                 // PK padded to %32

// workspace layout (float units)
#define OFF_H     0                         // fp32 9984*512
#define OFF_AB1   5111808                   // bf16 9984*512
#define OFF_AB2   (OFF_AB1 + 2555904)
#define OFF_QKVB  (OFF_AB2 + 2555904)       // bf16 9984*1536
#define OFF_FFNB  (OFF_QKVB + 7667712)      // bf16 9984*2048 (aliased: VtG / Xp+obs)
#define OFF_WB    (OFF_FFNB + 10223616)     // bf16 transposed weights
#define WS_FLOATS (OFF_WB + 9641984 + 16)

static __device__ __forceinline__ ushort_t f2b(float x) {
    union { float f; unsigned int u; } v; v.f = x;
    unsigned int r = v.u + 0x7FFFu + ((v.u >> 16) & 1u);
    return (ushort_t)(r >> 16);
}

static __device__ __forceinline__ void gload16(const ushort_t* g, ushort_t* l) {
    __builtin_amdgcn_global_load_lds(
        (const __attribute__((address_space(1))) void*)g,
        (__attribute__((address_space(3))) void*)l, 16, 0, 0);
}

__global__ void sentinel_kernel(float* out, int n) {
    int i = blockIdx.x * 256 + threadIdx.x;
    if (i < n) out[i] = 100.0f;
}

// ---------------- weight transpose+convert: [K][N] fp32 -> [N][K] bf16, per layer -------
__global__ __launch_bounds__(256) void transpose_cvt_kernel(
    const float* __restrict__ src, ushort_t* __restrict__ dst, int K, int N)
{
    __shared__ float tile[32][33];
    int layer = blockIdx.z;
    int n0 = blockIdx.x * 32, k0 = blockIdx.y * 32;
    int tx = threadIdx.x & 31, ty = threadIdx.x >> 5;   // 32 x 8
    const float* s = src + (size_t)layer * K * N;
    ushort_t* d = dst + (size_t)layer * N * K;
#pragma unroll
    for (int r = 0; r < 32; r += 8)
        tile[ty + r][tx] = s[(size_t)(k0 + ty + r) * N + n0 + tx];
    __syncthreads();
#pragma unroll
    for (int r = 0; r < 32; r += 8)
        d[(size_t)(n0 + ty + r) * K + k0 + tx] = f2b(tile[tx][ty + r]);
}

// patch_W [784][512] fp32 -> [512][800] bf16 (k-pad zeros)
__global__ __launch_bounds__(256) void transpose_patchw_kernel(
    const float* __restrict__ src, ushort_t* __restrict__ dst)
{
    __shared__ float tile[32][33];
    int n0 = blockIdx.x * 32, k0 = blockIdx.y * 32;
    int tx = threadIdx.x & 31, ty = threadIdx.x >> 5;
#pragma unroll
    for (int r = 0; r < 32; r += 8) {
        int k = k0 + ty + r;
        tile[ty + r][tx] = (k < PK) ? src[(size_t)k * D_ + n0 + tx] : 0.0f;
    }
    __syncthreads();
#pragma unroll
    for (int r = 0; r < 32; r += 8)
        dst[(size_t)(n0 + ty + r) * PKP + k0 + tx] = f2b(tile[tx][ty + r]);
}

// ---------------- patchify: frames fp32 -> Xp bf16 (9216 x 800) ----------------
__global__ void patchify_kernel(const float* __restrict__ frames, ushort_t* __restrict__ Xp) {
    int idx = blockIdx.x * 256 + threadIdx.x;
    if (idx >= OBS_ROWS * PKP) return;
    int r = idx / PKP, c = idx % PKP;
    if (c >= PK) { Xp[idx] = 0; return; }
    int bt = r / LOBS, p = r % LOBS;
    int gy = p / GP_, gx = p % GP_;
    int ch = c / (P_ * P_), rem = c % (P_ * P_);
    int py = rem / P_, px = rem % P_;
    size_t src = (((size_t)bt * C_ + ch) * HW_ + gy * P_ + py) * HW_ + gx * P_ + px;
    Xp[idx] = f2b(frames[src]);
}

// ---------------- MFMA GEMM, global_load_lds staging (m97 structure) ----------------
__global__ __launch_bounds__(256) void gemm_mfma(
    const ushort_t* __restrict__ A, const ushort_t* __restrict__ BT,
    const float* __restrict__ bias, const float* __restrict__ residual,
    float* __restrict__ Cf, ushort_t* __restrict__ Cb,
    int M, int N, int K, int do_gelu)
{
    __shared__ ushort_t As[128 * 32];
    __shared__ ushort_t Bs[128 * 32];
    int t = threadIdx.x, lane = t & 63, w = t >> 6;
    int row0 = blockIdx.y * 128, col0 = blockIdx.x * 128;
    int moff = (w & 1) << 6, noff = (w >> 1) << 6;
    int l16 = lane & 15, quad = lane >> 4;
    floatx4 acc[4][4];
#pragma unroll
    for (int i = 0; i < 4; ++i)
#pragma unroll
        for (int j = 0; j < 4; ++j) acc[i][j] = (floatx4){0.f, 0.f, 0.f, 0.f};
    int n0i = (2 * w) * 64 + lane;
    int n1i = (2 * w + 1) * 64 + lane;
    const ushort_t* gA0 = A + (size_t)(row0 + (n0i >> 2)) * K + (n0i & 3) * 8;
    const ushort_t* gA1 = A + (size_t)(row0 + (n1i >> 2)) * K + (n1i & 3) * 8;
    const ushort_t* gB0 = BT + (size_t)(col0 + (n0i >> 2)) * K + (n0i & 3) * 8;
    const ushort_t* gB1 = BT + (size_t)(col0 + (n1i >> 2)) * K + (n1i & 3) * 8;
    ushort_t* lA0 = &As[(2 * w) * 512];
    ushort_t* lA1 = &As[(2 * w + 1) * 512];
    ushort_t* lB0 = &Bs[(2 * w) * 512];
    ushort_t* lB1 = &Bs[(2 * w + 1) * 512];
    for (int k0 = 0; k0 < K; k0 += 32) {
        gload16(gA0, lA0);
        gload16(gA1, lA1);
        gload16(gB0, lB0);
        gload16(gB1, lB1);
        gA0 += 32; gA1 += 32; gB0 += 32; gB1 += 32;
        __syncthreads();
        bf16x8 af[4], bfv[4];
#pragma unroll
        for (int i = 0; i < 4; ++i)
            af[i] = *(const bf16x8*)&As[(moff + i * 16 + l16) * 32 + quad * 8];
#pragma unroll
        for (int j = 0; j < 4; ++j)
            bfv[j] = *(const bf16x8*)&Bs[(noff + j * 16 + l16) * 32 + quad * 8];
#pragma unroll
        for (int i = 0; i < 4; ++i)
#pragma unroll
            for (int j = 0; j < 4; ++j)
                acc[i][j] = __builtin_amdgcn_mfma_f32_16x16x32_bf16(af[i], bfv[j], acc[i][j], 0, 0, 0);
        __syncthreads();
    }
    int rquad = quad << 2;
#pragma unroll
    for (int j = 0; j < 4; ++j) {
        int col = col0 + noff + j * 16 + l16;
        float bv = bias ? bias[col] : 0.0f;
#pragma unroll
        for (int i = 0; i < 4; ++i) {
#pragma unroll
            for (int r = 0; r < 4; ++r) {
                int row = row0 + moff + i * 16 + rquad + r;
                float v = acc[i][j][r] + bv;
                if (do_gelu) v = 0.5f * v * (1.0f + erff(v * 0.70710678118654752f));
                if (residual) v += residual[(size_t)row * N + col];
                if (Cf) Cf[(size_t)row * N + col] = v;
                if (Cb) Cb[(size_t)row * N + col] = f2b(v);
            }
        }
    }
}

// ---------------- assemble tokens + embeddings -> h fp32 ----------------
__global__ void assemble_kernel(const float* __restrict__ obs,
                                const int* __restrict__ rtg,
                                const int* __restrict__ act,
                                const int* __restrict__ rew,
                                const float* __restrict__ retE,
                                const float* __restrict__ actE,
                                const float* __restrict__ rewE,
                                const float* __restrict__ posE,
                                const float* __restrict__ typeE,
                                float* __restrict__ h) {
    int idx = blockIdx.x * 256 + threadIdx.x;
    if (idx >= ROWS * D_) return;
    int d = idx & (D_ - 1);
    int bl = idx / D_;
    int l = bl % L_, b = bl / L_;
    int t = l / S_, off = l % S_;
    int bt = b * T_ + t;
    float v;
    int ty;
    if (off < LOBS) {
        v = obs[((size_t)bt * LOBS + off) * D_ + d];
        ty = 0;
    } else if (off == LOBS) {
        v = retE[(size_t)rtg[bt] * D_ + d];
        ty = 1;
    } else if (off == LOBS + 1) {
        v = actE[(size_t)act[bt] * D_ + d];
        ty = 2;
    } else {
        v = rewE[(size_t)rew[bt] * D_ + d];
        ty = 3;
    }
    v += posE[(size_t)l * D_ + d] + typeE[(size_t)ty * D_ + d];
    h[idx] = v;
}

// ---------------- LayerNorm fp32 in -> bf16 out ----------------
__global__ __launch_bounds__(256) void ln_fast(const float* __restrict__ x,
                                               const float* __restrict__ g,
                                               const float* __restrict__ bb,
                                               ushort_t* __restrict__ y) {
    int row = blockIdx.x;
    const float* xr = x + (size_t)row * D_;
    ushort_t* yr = y + (size_t)row * D_;
    int tid = threadIdx.x;
    float v0 = xr[tid], v1 = xr[tid + 256];
    __shared__ float red[4];
    int lane = tid & 63, wid = tid >> 6;
    float s = v0 + v1;
#pragma unroll
    for (int off = 32; off > 0; off >>= 1) s += __shfl_down(s, off, 64);
    if (lane == 0) red[wid] = s;
    __syncthreads();
    float mean = (red[0] + red[1] + red[2] + red[3]) * (1.0f / 512.0f);
    __syncthreads();
    float d0 = v0 - mean, d1 = v1 - mean;
    float vs = d0 * d0 + d1 * d1;
#pragma unroll
    for (int off = 32; off > 0; off >>= 1) vs += __shfl_down(vs, off, 64);
    if (lane == 0) red[wid] = vs;
    __syncthreads();
    float var = (red[0] + red[1] + red[2] + red[3]) * (1.0f / 512.0f);
    float rstd = rsqrtf(var + 1e-5f);
    yr[tid]       = f2b(d0 * rstd * g[tid]       + bb[tid]);
    yr[tid + 256] = f2b(d1 * rstd * g[tid + 256] + bb[tid + 256]);
}

// ---------------- V pre-transpose per layer: qkvb V -> VtG[bh][d][l] bf16 ------------
__global__ __launch_bounds__(256) void vt_prep(const ushort_t* __restrict__ qkvb,
                                               ushort_t* __restrict__ vtg)
{
    __shared__ ushort_t tl[32][33];
    int bh = blockIdx.z; int b = bh >> 3, hh = bh & 7;
    int l0 = blockIdx.x * 32, d0 = blockIdx.y * 32;
    int tx = threadIdx.x & 31, ty = threadIdx.x >> 5;
#pragma unroll
    for (int r = 0; r < 32; r += 8)
        tl[ty + r][tx] = qkvb[((size_t)b * L_ + l0 + ty + r) * 1536 + 1024 + hh * 64 + d0 + tx];
    __syncthreads();
#pragma unroll
    for (int r = 0; r < 32; r += 8)
        vtg[((size_t)bh * 64 + d0 + ty + r) * L_ + l0 + tx] = tl[tx][ty + r];
}

// ---------------- barrier-free MFMA flash attention, fixed-max softmax ----------------
__global__ __launch_bounds__(256) void attn_mfma(const ushort_t* __restrict__ qkvb,
                                                 const ushort_t* __restrict__ vtg,
                                                 ushort_t* __restrict__ outb)
{
    int bh = blockIdx.x; int hh = bh & 7, b = bh >> 3;
    int qt = 19 - blockIdx.y;            // long blocks first (tail scheduling)
    int q0 = qt << 6;
    int t = threadIdx.x, lane = t & 63, w = t >> 6;
    int l16 = lane & 15, quad = lane >> 4;
    __shared__ ushort_t Ps[64][72];
    const ushort_t* base = qkvb + (size_t)b * (L_ * 1536);
    const ushort_t* vbase = vtg + (size_t)bh * 64 * L_;
    int qrow_l = q0 + w * 16 + l16; if (qrow_l >= L_) qrow_l = L_ - 1;
    const ushort_t* qp = base + (size_t)qrow_l * 1536 + hh * 64 + quad * 8;
    bf16x8 aq0 = *(const bf16x8*)qp;
    bf16x8 aq1 = *(const bf16x8*)(qp + 32);
    int qg[4], stepq[4], obsq[4];
#pragma unroll
    for (int r = 0; r < 4; ++r) {
        qg[r] = q0 + w * 16 + quad * 4 + r;
        stepq[r] = qg[r] / S_;
        obsq[r] = (qg[r] - stepq[r] * S_) < LOBS;
    }
    int qlast = q0 + 63; if (qlast > L_ - 1) qlast = L_ - 1;
    int kend_max = qlast;
    int we = (qlast / S_) * S_ + LOBS - 1;
    if (we > kend_max) kend_max = we;
    int ntiles = (kend_max >> 6) + 1;

    float psum[4] = {0.f, 0.f, 0.f, 0.f};
    floatx4 O[4];
#pragma unroll
    for (int nb = 0; nb < 4; ++nb) O[nb] = (floatx4){0.f, 0.f, 0.f, 0.f};

    for (int kt = 0; kt < ntiles; ++kt) {
        int k0 = kt << 6;
        floatx4 sc4[4];
#pragma unroll
        for (int nb = 0; nb < 4; ++nb) {
            int krow = k0 + nb * 16 + l16; if (krow >= L_) krow = L_ - 1;
            const ushort_t* kp = base + (size_t)krow * 1536 + 512 + hh * 64 + quad * 8;
            bf16x8 bk0 = *(const bf16x8*)kp;
            bf16x8 bk1 = *(const bf16x8*)(kp + 32);
            floatx4 z = (floatx4){0.f, 0.f, 0.f, 0.f};
            z = __builtin_amdgcn_mfma_f32_16x16x32_bf16(aq0, bk0, z, 0, 0, 0);
            z = __builtin_amdgcn_mfma_f32_16x16x32_bf16(aq1, bk1, z, 0, 0, 0);
            sc4[nb] = z;
        }
        if (kt < qt) {
#pragma unroll
            for (int nb = 0; nb < 4; ++nb)
#pragma unroll
                for (int r = 0; r < 4; ++r) {
                    float p = __expf(sc4[nb][r] * 0.125f);
                    psum[r] += p;
                    Ps[w * 16 + quad * 4 + r][nb * 16 + l16] = f2b(p);
                }
        } else {
#pragma unroll
            for (int nb = 0; nb < 4; ++nb) {
                int kg = k0 + nb * 16 + l16;
                int stepk = kg / S_;
                int kobs = (kg - stepk * S_) < LOBS;
#pragma unroll
                for (int r = 0; r < 4; ++r) {
                    int allowed = (kg <= qg[r]) || (obsq[r] && kobs && (stepk == stepq[r]));
                    float p = allowed ? __expf(sc4[nb][r] * 0.125f) : 0.0f;
                    psum[r] += p;
                    Ps[w * 16 + quad * 4 + r][nb * 16 + l16] = f2b(p);
                }
            }
        }
        bf16x8 ap0 = *(const bf16x8*)&Ps[w * 16 + l16][quad * 8];
        bf16x8 ap1 = *(const bf16x8*)&Ps[w * 16 + l16][quad * 8 + 32];
        int c0 = k0 + quad * 8;      if (c0 > L_ - 8) c0 = L_ - 8;
        int c1 = k0 + 32 + quad * 8; if (c1 > L_ - 8) c1 = L_ - 8;
#pragma unroll
        for (int nb = 0; nb < 4; ++nb) {
            const ushort_t* vp = vbase + (size_t)(nb * 16 + l16) * L_;
            bf16x8 bv0 = *(const bf16x8*)(vp + c0);
            bf16x8 bv1 = *(const bf16x8*)(vp + c1);
            O[nb] = __builtin_amdgcn_mfma_f32_16x16x32_bf16(ap0, bv0, O[nb], 0, 0, 0);
            O[nb] = __builtin_amdgcn_mfma_f32_16x16x32_bf16(ap1, bv1, O[nb], 0, 0, 0);
        }
    }
#pragma unroll
    for (int off = 1; off < 16; off <<= 1)
#pragma unroll
        for (int r = 0; r < 4; ++r)
            psum[r] += __shfl_xor(psum[r], off, 64);
#pragma unroll
    for (int r = 0; r < 4; ++r) {
        if (qg[r] < L_) {
            float inv = 1.0f / psum[r];
#pragma unroll
            for (int nb = 0; nb < 4; ++nb)
                outb[((size_t)b * L_ + qg[r]) * 512 + hh * 64 + nb * 16 + l16] =
                    f2b(O[nb][r] * inv);
        }
    }
}

// ---------------- heads: LDS-staged, unrolled; one block per (b,t) ----------------
__global__ __launch_bounds__(256) void heads_fast(const float* __restrict__ h,
                            const float* __restrict__ hW_ret, const float* __restrict__ hb_ret,
                            const float* __restrict__ hW_act, const float* __restrict__ hb_act,
                            const float* __restrict__ hW_rew, const float* __restrict__ hb_rew,
                            float* __restrict__ out) {
    int bt = blockIdx.x;
    int b = bt >> 5, t = bt & 31;
    __shared__ float hr[D_], ha[D_], hw[D_];
    size_t base = ((size_t)b * L_ + (size_t)t * S_) * D_;
    int tid = threadIdx.x;
    for (int i = tid; i < D_; i += 256) {
        hr[i] = h[base + (size_t)(LOBS - 1) * D_ + i];
        ha[i] = h[base + (size_t)LOBS * D_ + i];
        hw[i] = h[base + (size_t)(LOBS + 1) * D_ + i];
    }
    __syncthreads();
    if (tid < NRET) {
        float acc = hb_ret[tid];
#pragma unroll 16
        for (int k = 0; k < D_; ++k) acc = fmaf(hr[k], hW_ret[(size_t)k * NRET + tid], acc);
        out[(size_t)bt * NRET + tid] = acc;
    } else if (tid < NRET + NACT) {
        int n = tid - NRET;
        float acc = hb_act[n];
#pragma unroll 16
        for (int k = 0; k < D_; ++k) acc = fmaf(ha[k], hW_act[(size_t)k * NACT + n], acc);
        out[(size_t)(B_ * T_ * NRET) + (size_t)bt * NACT + n] = acc;
    } else if (tid < NRET + NACT + NREW) {
        int n = tid - NRET - NACT;
        float acc = hb_rew[n];
#pragma unroll 16
        for (int k = 0; k < D_; ++k) acc = fmaf(hw[k], hW_rew[(size_t)k * NREW + n], acc);
        out[(size_t)(B_ * T_ * (NRET + NACT)) + (size_t)bt * NREW + n] = acc;
    }
}

static inline int cdiv_i(long long a, int b) { return (int)((a + b - 1) / b); }

extern "C" void kernel_launch(void* const* d_in, const int* in_sizes, int n_in,
                              void* d_out, int out_size, void* d_ws, size_t ws_size,
                              hipStream_t stream) {
    if (ws_size < (size_t)WS_FLOATS * sizeof(float)) {
        sentinel_kernel<<<(out_size + 255) / 256, 256, 0, stream>>>((float*)d_out, out_size);
        return;
    }
    const float* frames  = (const float*)d_in[0];
    const int*   rtg     = (const int*)d_in[1];
    const int*   actions = (const int*)d_in[2];
    const int*   rewards = (const int*)d_in[3];

    float* ws   = (float*)d_ws;
    float* h    = ws + OFF_H;
    ushort_t* ab1  = (ushort_t*)(ws + OFF_AB1);
    ushort_t* ab2  = (ushort_t*)(ws + OFF_AB2);
    ushort_t* qkvb = (ushort_t*)(ws + OFF_QKVB);
    ushort_t* ffnb = (ushort_t*)(ws + OFF_FFNB);
    ushort_t* vtg  = (ushort_t*)(ws + OFF_FFNB);
    ushort_t* xpb  = (ushort_t*)(ws + OFF_FFNB);
    float*    obs  = ws + OFF_FFNB + 3686400;
    ushort_t* wpatchT = (ushort_t*)(ws + OFF_WB);
    ushort_t* wqkvT = wpatchT + PKP * D_;
    ushort_t* woT   = wqkvT + NL_ * D_ * 3 * D_;
    ushort_t* w1T   = woT + NL_ * D_ * D_;
    ushort_t* w2T   = w1T + NL_ * D_ * DFF_;

    // ---- weight transpose + fp32->bf16 ----
    transpose_patchw_kernel<<<dim3(16, 25), 256, 0, stream>>>((const float*)d_in[4], wpatchT);
    transpose_cvt_kernel<<<dim3(48, 16, NL_), 256, 0, stream>>>((const float*)d_in[11], wqkvT, D_, 3 * D_);
    transpose_cvt_kernel<<<dim3(16, 16, NL_), 256, 0, stream>>>((const float*)d_in[13], woT, D_, D_);
    transpose_cvt_kernel<<<dim3(64, 16, NL_), 256, 0, stream>>>((const float*)d_in[19], w1T, D_, DFF_);
    transpose_cvt_kernel<<<dim3(16, 64, NL_), 256, 0, stream>>>((const float*)d_in[21], w2T, DFF_, D_);

    // ---- patchify + patch embed ----
    patchify_kernel<<<cdiv_i((long long)OBS_ROWS * PKP, 256), 256, 0, stream>>>(frames, xpb);
    gemm_mfma<<<dim3(D_ / 128, OBS_ROWS / 128), 256, 0, stream>>>(
        xpb, wpatchT, (const float*)d_in[5], nullptr, obs, nullptr, OBS_ROWS, D_, PKP, 0);

    // ---- assemble sequence ----
    assemble_kernel<<<cdiv_i((long long)ROWS * D_, 256), 256, 0, stream>>>(
        obs, rtg, actions, rewards,
        (const float*)d_in[6], (const float*)d_in[7], (const float*)d_in[8],
        (const float*)d_in[9], (const float*)d_in[10], h);

    // ---- transformer layers ----
    for (int i = 0; i < NL_; ++i) {
        ln_fast<<<ROWS, 256, 0, stream>>>(h, (const float*)d_in[15] + i * D_,
                                          (const float*)d_in[16] + i * D_, ab1);
        gemm_mfma<<<dim3(3 * D_ / 128, ROWS / 128), 256, 0, stream>>>(
            ab1, wqkvT + (size_t)i * D_ * 3 * D_, (const float*)d_in[12] + i * 3 * D_,
            nullptr, nullptr, qkvb, ROWS, 3 * D_, D_, 0);
        vt_prep<<<dim3(39, 2, 64), 256, 0, stream>>>(qkvb, vtg);
        attn_mfma<<<dim3(64, 20), 256, 0, stream>>>(qkvb, vtg, ab2);
        gemm_mfma<<<dim3(D_ / 128, ROWS / 128), 256, 0, stream>>>(
            ab2, woT + (size_t)i * D_ * D_, (const float*)d_in[14] + i * D_,
            h, h, nullptr, ROWS, D_, D_, 0);
        ln_fast<<<ROWS, 256, 0, stream>>>(h, (const float*)d_in[17] + i * D_,
                                          (const float*)d_in[18] + i * D_, ab1);
        gemm_mfma<<<dim3(DFF_ / 128, ROWS / 128), 256, 0, stream>>>(
            ab1, w1T + (size_t)i * D_ * DFF_, (const float*)d_in[20] + i * DFF_,
            nullptr, nullptr, ffnb, ROWS, DFF_, D_, 1);
        gemm_mfma<<<dim3(D_ / 128, ROWS / 128), 256, 0, stream>>>(
            ffnb, w2T + (size_t)i * DFF_ * D_, (const float*)d_in[22] + i * D_,
            h, h, nullptr, ROWS, D_, DFF_, 0);
    }

    // ---- heads ----
    heads_fast<<<B_ * T_, 256, 0, stream>>>(h,
        (const float*)d_in[23], (const float*)d_in[24],
        (const float*)d_in[25], (const float*)d_in[26],
        (const float*)d_in[27], (const float*)d_in[28], (float*)d_out);
}